// Round 1
// baseline (1664.286 us; speedup 1.0000x reference)
//
#include <hip/hip_runtime.h>
#include <hip/hip_bf16.h>
#include <cstdint>

#define D_MODEL 768
#define D_STATE 16
#define D_CONV  4
#define D_INNER 1536
#define BATCH   2
#define SEQ     2048
#define M_ROWS  (BATCH*SEQ)          // 4096
#define XZ_LD   (2*D_INNER)          // 3072
#define XDBL_N  (D_INNER + 2*D_STATE) // 1568

__device__ __forceinline__ float silu_f(float v) {
    return v / (1.f + __expf(-v));
}

// C[m,n] = act( sum_k A[m,k]*W[n,k] + bias[n] )
// A: (M,K) row-major with leading dim lda; W: (N,K) row-major; C: ldc leading dim.
// ACT: 0 = none, 1 = softplus
template<int ACT>
__global__ __launch_bounds__(256) void gemm_f32(
    const float* __restrict__ A, int lda,
    const float* __restrict__ W,
    const float* __restrict__ bias,
    float* __restrict__ C, int ldc,
    int M, int N, int K)
{
    constexpr int BM = 128, BN = 64, BK = 16;
    __shared__ float As[BK][BM + 4];
    __shared__ float Bs[BK][BN + 4];
    const int bm = blockIdx.y * BM;
    const int bn = blockIdx.x * BN;
    const int tid = threadIdx.x;
    const int tx = tid & 15;   // n-group: cols tx*4 .. +3
    const int ty = tid >> 4;   // m-group: rows ty*8 .. +7
    float acc[8][4] = {};

    for (int k0 = 0; k0 < K; k0 += BK) {
        // A tile: 128 rows x 16 k = 512 float4, 2 per thread
        #pragma unroll
        for (int i = 0; i < 2; ++i) {
            int f4  = i * 256 + tid;
            int row = f4 >> 2;
            int kq  = (f4 & 3) << 2;
            float4 v = *reinterpret_cast<const float4*>(
                &A[(size_t)(bm + row) * lda + k0 + kq]);
            As[kq+0][row] = v.x; As[kq+1][row] = v.y;
            As[kq+2][row] = v.z; As[kq+3][row] = v.w;
        }
        // W tile: 64 rows x 16 k = 256 float4, 1 per thread (guard N edge)
        {
            int row = tid >> 2;
            int kq  = (tid & 3) << 2;
            int gn  = bn + row;
            float4 v = make_float4(0.f, 0.f, 0.f, 0.f);
            if (gn < N)
                v = *reinterpret_cast<const float4*>(&W[(size_t)gn * K + k0 + kq]);
            Bs[kq+0][row] = v.x; Bs[kq+1][row] = v.y;
            Bs[kq+2][row] = v.z; Bs[kq+3][row] = v.w;
        }
        __syncthreads();
        #pragma unroll
        for (int k = 0; k < BK; ++k) {
            float a[8], b[4];
            #pragma unroll
            for (int i = 0; i < 8; ++i) a[i] = As[k][ty*8 + i];
            #pragma unroll
            for (int j = 0; j < 4; ++j) b[j] = Bs[k][tx*4 + j];
            #pragma unroll
            for (int i = 0; i < 8; ++i)
                #pragma unroll
                for (int j = 0; j < 4; ++j)
                    acc[i][j] = fmaf(a[i], b[j], acc[i][j]);
        }
        __syncthreads();
    }

    #pragma unroll
    for (int i = 0; i < 8; ++i) {
        int gm = bm + ty*8 + i;
        #pragma unroll
        for (int j = 0; j < 4; ++j) {
            int gn = bn + tx*4 + j;
            if (gn < N) {
                float v = acc[i][j];
                if (bias) v += bias[gn];
                if (ACT == 1) v = (v > 20.f) ? v : log1pf(__expf(v));
                C[(size_t)gm * ldc + gn] = v;
            }
        }
    }
}

// depthwise causal conv (k=4) + bias + SiLU; reads x_in = xz[:, :1536]
__global__ __launch_bounds__(256) void conv_silu_kernel(
    const float* __restrict__ xz,
    const float* __restrict__ cw,   // (D_INNER,1,4)
    const float* __restrict__ cb,   // (D_INNER,)
    float* __restrict__ xc)         // (M_ROWS, D_INNER)
{
    int idx = blockIdx.x * 256 + threadIdx.x;   // over M_ROWS * D_INNER/4
    int d4  = idx % (D_INNER / 4);
    int row = idx / (D_INNER / 4);
    if (row >= M_ROWS) return;
    int l = row & (SEQ - 1);
    int d = d4 * 4;
    float4 acc = make_float4(cb[d], cb[d+1], cb[d+2], cb[d+3]);
    #pragma unroll
    for (int jj = 0; jj < D_CONV; ++jj) {
        int ls = l + jj - (D_CONV - 1);
        if (ls >= 0) {
            const float4 xv = *reinterpret_cast<const float4*>(
                &xz[(size_t)(row + jj - (D_CONV - 1)) * XZ_LD + d]);
            acc.x = fmaf(xv.x, cw[(d+0)*D_CONV + jj], acc.x);
            acc.y = fmaf(xv.y, cw[(d+1)*D_CONV + jj], acc.y);
            acc.z = fmaf(xv.z, cw[(d+2)*D_CONV + jj], acc.z);
            acc.w = fmaf(xv.w, cw[(d+3)*D_CONV + jj], acc.w);
        }
    }
    acc.x = silu_f(acc.x); acc.y = silu_f(acc.y);
    acc.z = silu_f(acc.z); acc.w = silu_f(acc.w);
    *reinterpret_cast<float4*>(&xc[(size_t)row * D_INNER + d]) = acc;
}

// Selective scan. Block = 256 threads = 16 d-channels x 16 states.
// Writes y_final = (sum_n h*C + xconv*D) * silu(z) into xz[:, :D_INNER]
// (the dead x_in region), row stride XZ_LD.
__global__ __launch_bounds__(256) void scan_kernel(
    const float* __restrict__ delta,   // (M_ROWS, D_INNER)
    const float* __restrict__ xdbl,    // (M_ROWS, XDBL_N): B at +1536, C at +1552
    const float* __restrict__ xconv,   // (M_ROWS, D_INNER)
    float* xz,                         // z read at +1536; y written at col<1536
    const float* __restrict__ A_log,   // (D_INNER, D_STATE)
    const float* __restrict__ D_param) // (D_INNER,)
{
    constexpr int LCH = 64;
    __shared__ float sdl[16][68];
    __shared__ float sxc[16][68];
    __shared__ float szz[16][68];
    __shared__ float sB[16][68];
    __shared__ float sC[16][68];

    const int b    = blockIdx.x / (D_INNER / 16);
    const int dblk = blockIdx.x % (D_INNER / 16);
    const int d0   = dblk * 16;
    const int tid  = threadIdx.x;
    const int n    = tid & 15;   // state index
    const int dl   = tid >> 4;   // d-local
    const int d    = d0 + dl;

    const float Areg = -__expf(A_log[d * D_STATE + n]);
    const float Dp   = D_param[d];
    float h = 0.f;

    const int ld_c  = tid & 15;
    const int ld_j0 = tid >> 4;

    for (int l0 = 0; l0 < SEQ; l0 += LCH) {
        __syncthreads();
        #pragma unroll
        for (int r = 0; r < LCH / 16; ++r) {
            int j = ld_j0 + r * 16;
            size_t row = (size_t)(b * SEQ + l0 + j);
            sdl[ld_c][j] = delta[row * D_INNER + d0 + ld_c];
            sxc[ld_c][j] = xconv[row * D_INNER + d0 + ld_c];
            szz[ld_c][j] = xz[row * XZ_LD + D_INNER + d0 + ld_c];
            sB[ld_c][j]  = xdbl[row * XDBL_N + D_INNER + ld_c];
            sC[ld_c][j]  = xdbl[row * XDBL_N + D_INNER + D_STATE + ld_c];
        }
        __syncthreads();
        for (int j = 0; j < LCH; ++j) {
            float dlt = sdl[dl][j];
            float xv  = sxc[dl][j];
            float bv  = sB[n][j];
            float cv  = sC[n][j];
            float dA  = __expf(dlt * Areg);
            h = fmaf(dA, h, dlt * bv * xv);
            float p = h * cv;
            p += __shfl_xor(p, 1);
            p += __shfl_xor(p, 2);
            p += __shfl_xor(p, 4);
            p += __shfl_xor(p, 8);
            if (n == 0) {
                float zv = szz[dl][j];
                float y  = (p + xv * Dp) * silu_f(zv);
                xz[(size_t)(b * SEQ + l0 + j) * XZ_LD + d0 + dl] = y;
            }
        }
    }
}

extern "C" void kernel_launch(void* const* d_in, const int* in_sizes, int n_in,
                              void* d_out, int out_size, void* d_ws, size_t ws_size,
                              hipStream_t stream) {
    const float* x         = (const float*)d_in[0];
    const float* in_proj_w = (const float*)d_in[1];
    const float* conv_w    = (const float*)d_in[2];
    const float* conv_b    = (const float*)d_in[3];
    const float* x_proj_w  = (const float*)d_in[4];
    const float* dt_proj_w = (const float*)d_in[5];
    const float* dt_proj_b = (const float*)d_in[6];
    const float* A_log     = (const float*)d_in[7];
    const float* D_param   = (const float*)d_in[8];
    const float* out_proj_w= (const float*)d_in[9];
    float* out = (float*)d_out;

    float* ws    = (float*)d_ws;
    float* xz    = ws;                                  // (4096,3072)
    float* xconv = xz    + (size_t)M_ROWS * XZ_LD;      // (4096,1536)
    float* xdbl  = xconv + (size_t)M_ROWS * D_INNER;    // (4096,1568)
    float* delta = xdbl  + (size_t)M_ROWS * XDBL_N;     // (4096,1536)
    // total = 4096*7712 floats = 126.35 MB

    // 1) xz = x @ in_proj_w^T    (M=4096, K=768, N=3072)
    gemm_f32<0><<<dim3(XZ_LD/64, M_ROWS/128), 256, 0, stream>>>(
        x, D_MODEL, in_proj_w, nullptr, xz, XZ_LD, M_ROWS, XZ_LD, D_MODEL);

    // 2) x_conv = silu(depthwise_conv(x_in) + conv_b)
    conv_silu_kernel<<<(M_ROWS * (D_INNER/4)) / 256, 256, 0, stream>>>(
        xz, conv_w, conv_b, xconv);

    // 3) x_dbl = x_conv @ x_proj_w^T   (K=1536, N=1568)
    gemm_f32<0><<<dim3((XDBL_N + 63)/64, M_ROWS/128), 256, 0, stream>>>(
        xconv, D_INNER, x_proj_w, nullptr, xdbl, XDBL_N, M_ROWS, XDBL_N, D_INNER);

    // 4) delta = softplus(delta_raw @ dt_proj_w^T + dt_proj_b)  (K=1536, N=1536)
    gemm_f32<1><<<dim3(D_INNER/64, M_ROWS/128), 256, 0, stream>>>(
        xdbl, XDBL_N, dt_proj_w, dt_proj_b, delta, D_INNER, M_ROWS, D_INNER, D_INNER);

    // 5) selective scan; y_final -> xz[:, :1536]
    scan_kernel<<<BATCH * (D_INNER/16), 256, 0, stream>>>(
        delta, xdbl, xconv, xz, A_log, D_param);

    // 6) out = y_final @ out_proj_w^T   (K=1536, N=768)
    gemm_f32<0><<<dim3(D_MODEL/64, M_ROWS/128), 256, 0, stream>>>(
        xz, XZ_LD, out_proj_w, nullptr, out, D_MODEL, M_ROWS, D_MODEL, D_INNER);
}

// Round 2
// 477.524 us; speedup vs baseline: 3.4852x; 3.4852x over previous
//
#include <hip/hip_runtime.h>
#include <hip/hip_bf16.h>
#include <cstdint>

#define D_MODEL 768
#define D_STATE 16
#define D_CONV  4
#define D_INNER 1536
#define BATCH   2
#define SEQ     2048
#define M_ROWS  (BATCH*SEQ)            // 4096
#define XZ_LD   (2*D_INNER)            // 3072
#define XDBL_N  (D_INNER + 2*D_STATE)  // 1568
#define XPW_NPAD 1664                  // 1568 padded to 13*128
#define NCHUNK  32
#define CH      64
#define NDBLK   (D_INNER/16)           // 96

typedef __attribute__((ext_vector_type(8))) __bf16 bf16x8;
typedef __attribute__((ext_vector_type(4))) float f32x4;
typedef const __attribute__((address_space(1))) void* as1cv;
typedef __attribute__((address_space(3))) void* as3v;

__device__ __forceinline__ ushort f2bf(float f) {
    uint32_t u = __float_as_uint(f);
    return (ushort)((u + 0x7FFFu + ((u >> 16) & 1u)) >> 16);
}
__device__ __forceinline__ float bf2f(ushort h) {
    return __uint_as_float(((uint32_t)h) << 16);
}
__device__ __forceinline__ float silu_f(float v) { return v / (1.f + __expf(-v)); }

// ---------------- split kernels: f32 -> bf16 hi + bf16 lo ----------------
__global__ __launch_bounds__(256) void split4(const float* __restrict__ src,
                                              ushort* __restrict__ hi, ushort* __restrict__ lo,
                                              int n4) {
    int i = blockIdx.x * 256 + threadIdx.x;
    if (i >= n4) return;
    float4 v = ((const float4*)src)[i];
    ushort4 h, l;
    h.x = f2bf(v.x); l.x = f2bf(v.x - bf2f(h.x));
    h.y = f2bf(v.y); l.y = f2bf(v.y - bf2f(h.y));
    h.z = f2bf(v.z); l.z = f2bf(v.z - bf2f(h.z));
    h.w = f2bf(v.w); l.w = f2bf(v.w - bf2f(h.w));
    ((ushort4*)hi)[i] = h;
    ((ushort4*)lo)[i] = l;
}

// x_proj_w (1568,1536) -> padded (1664,1536), rows >=1568 zero
__global__ __launch_bounds__(256) void split_pad_xpw(const float* __restrict__ src,
                                                     ushort* __restrict__ hi, ushort* __restrict__ lo) {
    int i = blockIdx.x * 256 + threadIdx.x;      // < 1664*384
    int row = i / (D_INNER/4);
    float4 v = make_float4(0.f, 0.f, 0.f, 0.f);
    if (row < XDBL_N) v = ((const float4*)src)[i];
    ushort4 h, l;
    h.x = f2bf(v.x); l.x = f2bf(v.x - bf2f(h.x));
    h.y = f2bf(v.y); l.y = f2bf(v.y - bf2f(h.y));
    h.z = f2bf(v.z); l.z = f2bf(v.z - bf2f(h.z));
    h.w = f2bf(v.w); l.w = f2bf(v.w - bf2f(h.w));
    ((ushort4*)hi)[i] = h;
    ((ushort4*)lo)[i] = l;
}

// ---------------- split-bf16 MFMA GEMM ----------------
// C[m,n] = act( sum_k A[m,k]*W[n,k] + bias[n] ),  A=(M,K) as hi/lo bf16, W=(Npad,K) hi/lo bf16.
// OM==0: write f32 to Cf (ld ldc) for col<N.
// OM==1: col<1536 -> bf16 hi/lo split to Oh/Ol (ld 1536); 1536<=col<N -> f32 to Cf (ld 32, col-1536).
template<int ACT, int OM>
__global__ __launch_bounds__(256) void gemm_mfma(
    const ushort* __restrict__ Ah, const ushort* __restrict__ Al,
    const ushort* __restrict__ Wh, const ushort* __restrict__ Wl,
    const float* __restrict__ bias,
    float* __restrict__ Cf, int ldc,
    ushort* __restrict__ Oh, ushort* __restrict__ Ol,
    int N, int K)
{
    __shared__ ushort lds[4][128*64];   // Ah, Al, Wh, Wl tiles; 64 KiB total
    const int tid = threadIdx.x, lane = tid & 63, wave = tid >> 6;
    const int bm = blockIdx.y * 128, bn = blockIdx.x * 128;
    const int wr = wave >> 1, wc = wave & 1;          // wave -> 64x64 subtile
    const int r15 = lane & 15, q = lane >> 4;
    const int xorv = (lane & 7) << 4;                  // read-side XOR swizzle
    f32x4 acc[4][4] = {};

    // staging geometry: linear LDS offset -> (row, colb); global col pre-swizzled (rule 21)
    int srowv[4], scolb[4], soff[4];
    #pragma unroll
    for (int i = 0; i < 4; ++i) {
        int off = wave*4096 + i*1024 + lane*16;
        int row = off >> 7;
        srowv[i] = row;
        scolb[i] = (off & 127) ^ ((row & 7) << 4);
        soff[i]  = wave*4096 + i*1024;                 // wave-uniform LDS base
    }

    for (int k0 = 0; k0 < K; k0 += 64) {
        if (k0) __syncthreads();
        #pragma unroll
        for (int i = 0; i < 4; ++i) {
            size_t arow = ((size_t)(bm + srowv[i]) * K + k0) * 2;
            size_t brow = ((size_t)(bn + srowv[i]) * K + k0) * 2;
            __builtin_amdgcn_global_load_lds((as1cv)((const char*)Ah + arow + scolb[i]),
                                             (as3v)((char*)lds[0] + soff[i]), 16, 0, 0);
            __builtin_amdgcn_global_load_lds((as1cv)((const char*)Al + arow + scolb[i]),
                                             (as3v)((char*)lds[1] + soff[i]), 16, 0, 0);
            __builtin_amdgcn_global_load_lds((as1cv)((const char*)Wh + brow + scolb[i]),
                                             (as3v)((char*)lds[2] + soff[i]), 16, 0, 0);
            __builtin_amdgcn_global_load_lds((as1cv)((const char*)Wl + brow + scolb[i]),
                                             (as3v)((char*)lds[3] + soff[i]), 16, 0, 0);
        }
        __syncthreads();   // drains vmcnt before use
        #pragma unroll
        for (int kk = 0; kk < 2; ++kk) {
            const int kb = kk*64 + q*16;
            bf16x8 ah[4], al[4], bh[4], bl[4];
            #pragma unroll
            for (int m = 0; m < 4; ++m) {
                int row = wr*64 + m*16 + r15;
                int sc = row*128 + (kb ^ xorv);
                ah[m] = *(const bf16x8*)((const char*)lds[0] + sc);
                al[m] = *(const bf16x8*)((const char*)lds[1] + sc);
            }
            #pragma unroll
            for (int n = 0; n < 4; ++n) {
                int row = wc*64 + n*16 + r15;
                int sc = row*128 + (kb ^ xorv);
                bh[n] = *(const bf16x8*)((const char*)lds[2] + sc);
                bl[n] = *(const bf16x8*)((const char*)lds[3] + sc);
            }
            #pragma unroll
            for (int m = 0; m < 4; ++m)
                #pragma unroll
                for (int n = 0; n < 4; ++n) {
                    acc[m][n] = __builtin_amdgcn_mfma_f32_16x16x32_bf16(ah[m], bh[n], acc[m][n], 0, 0, 0);
                    acc[m][n] = __builtin_amdgcn_mfma_f32_16x16x32_bf16(ah[m], bl[n], acc[m][n], 0, 0, 0);
                    acc[m][n] = __builtin_amdgcn_mfma_f32_16x16x32_bf16(al[m], bh[n], acc[m][n], 0, 0, 0);
                }
        }
    }

    #pragma unroll
    for (int m = 0; m < 4; ++m) {
        #pragma unroll
        for (int n = 0; n < 4; ++n) {
            int col = bn + wc*64 + n*16 + r15;
            if (col >= N) continue;
            float bv = bias ? bias[col] : 0.f;
            #pragma unroll
            for (int r = 0; r < 4; ++r) {
                int rowg = bm + wr*64 + m*16 + q*4 + r;
                float v = acc[m][n][r] + bv;
                if (ACT == 1) v = (v > 20.f) ? v : log1pf(__expf(v));
                if (OM == 0) {
                    Cf[(size_t)rowg * ldc + col] = v;
                } else {
                    if (col < D_INNER) {
                        ushort hh = f2bf(v);
                        size_t o = (size_t)rowg * D_INNER + col;
                        Oh[o] = hh;
                        Ol[o] = f2bf(v - bf2f(hh));
                    } else {
                        Cf[(size_t)rowg * 32 + (col - D_INNER)] = v;
                    }
                }
            }
        }
    }
}

// ---------------- depthwise causal conv (k=4) + bias + SiLU -> bf16 hi/lo ----------------
__global__ __launch_bounds__(256) void conv_silu(
    const float* __restrict__ xz,
    const float* __restrict__ cw, const float* __restrict__ cb,
    ushort* __restrict__ xch, ushort* __restrict__ xcl)
{
    int idx = blockIdx.x * 256 + threadIdx.x;   // over M_ROWS * 384
    int d4  = idx % (D_INNER / 4);
    int row = idx / (D_INNER / 4);
    int l = row & (SEQ - 1);
    int d = d4 * 4;
    float4 acc = make_float4(cb[d], cb[d+1], cb[d+2], cb[d+3]);
    #pragma unroll
    for (int jj = 0; jj < D_CONV; ++jj) {
        int ls = l + jj - (D_CONV - 1);
        if (ls >= 0) {
            const float4 xv = *reinterpret_cast<const float4*>(
                &xz[(size_t)(row + jj - (D_CONV - 1)) * XZ_LD + d]);
            acc.x = fmaf(xv.x, cw[(d+0)*D_CONV + jj], acc.x);
            acc.y = fmaf(xv.y, cw[(d+1)*D_CONV + jj], acc.y);
            acc.z = fmaf(xv.z, cw[(d+2)*D_CONV + jj], acc.z);
            acc.w = fmaf(xv.w, cw[(d+3)*D_CONV + jj], acc.w);
        }
    }
    acc.x = silu_f(acc.x); acc.y = silu_f(acc.y);
    acc.z = silu_f(acc.z); acc.w = silu_f(acc.w);
    ushort4 h, l4;
    h.x = f2bf(acc.x); l4.x = f2bf(acc.x - bf2f(h.x));
    h.y = f2bf(acc.y); l4.y = f2bf(acc.y - bf2f(h.y));
    h.z = f2bf(acc.z); l4.z = f2bf(acc.z - bf2f(h.z));
    h.w = f2bf(acc.w); l4.w = f2bf(acc.w - bf2f(h.w));
    size_t o = ((size_t)row * D_INNER + d) >> 2;
    ((ushort4*)xch)[o] = h;
    ((ushort4*)xcl)[o] = l4;
}

// ---------------- chunked selective scan ----------------
// pass1: per chunk, local scan from h=0: P = prod dA, Hc = local h_end
__global__ __launch_bounds__(256) void scan_pass1(
    const float* __restrict__ delta,   // ld XZ_LD (aliased into xz cols 0..1535)
    const float* __restrict__ bc,      // (M_ROWS,32): B at +0, C at +16
    const ushort* __restrict__ xch, const ushort* __restrict__ xcl,
    const float* __restrict__ A_log,
    float* __restrict__ Pc, float* __restrict__ Hc)
{
    __shared__ float sdl[16][CH+4], sxc[16][CH+4], sB[16][CH+4];
    int blk = blockIdx.x;
    int dblk = blk % NDBLK; int c = (blk / NDBLK) % NCHUNK; int b = blk / (NDBLK*NCHUNK);
    int d0 = dblk * 16, tid = threadIdx.x;
    int n = tid & 15, dl = tid >> 4, d = d0 + dl;
    float Areg = -__expf(A_log[d * D_STATE + n]);
    int ld_c = tid & 15, ld_j0 = tid >> 4;
    int base_l = b * SEQ + c * CH;
    #pragma unroll
    for (int r = 0; r < CH/16; ++r) {
        int j = ld_j0 + r * 16;
        size_t row = (size_t)(base_l + j);
        sdl[ld_c][j] = delta[row * XZ_LD + d0 + ld_c];
        sxc[ld_c][j] = bf2f(xch[row * D_INNER + d0 + ld_c]) + bf2f(xcl[row * D_INNER + d0 + ld_c]);
        sB[ld_c][j]  = bc[row * 32 + ld_c];
    }
    __syncthreads();
    float h = 0.f, P = 1.f;
    for (int j = 0; j < CH; ++j) {
        float dlt = sdl[dl][j];
        float dA  = __expf(dlt * Areg);
        h = fmaf(dA, h, dlt * sB[n][j] * sxc[dl][j]);
        P *= dA;
    }
    size_t o = (size_t)(b * NCHUNK + c) * (D_INNER * D_STATE) + d0 * D_STATE + tid;
    Pc[o] = P; Hc[o] = h;
}

// pass2: tiny cross-chunk recurrence; Hin[c] = h entering chunk c
__global__ __launch_bounds__(256) void scan_pass2(
    const float* __restrict__ Pc, const float* __restrict__ Hc, float* __restrict__ Hin)
{
    int t = blockIdx.x * 256 + threadIdx.x;     // < BATCH * D_INNER * D_STATE
    int b = t / (D_INNER * D_STATE);
    int dn = t % (D_INNER * D_STATE);
    float h = 0.f;
    for (int c = 0; c < NCHUNK; ++c) {
        size_t o = (size_t)(b * NCHUNK + c) * (D_INNER * D_STATE) + dn;
        Hin[o] = h;
        h = fmaf(Pc[o], h, Hc[o]);
    }
}

// pass3: replay chunk with true h_in, fuse y = (sum_n h*C + xc*D)*silu(z), write y as bf16 hi/lo
__global__ __launch_bounds__(256) void scan_pass3(
    const float* __restrict__ delta, const float* __restrict__ bc,
    const ushort* __restrict__ xch, const ushort* __restrict__ xcl,
    const float* __restrict__ xz,    // z at col +D_INNER
    const float* __restrict__ A_log, const float* __restrict__ Dpar,
    const float* __restrict__ Hin,
    ushort* __restrict__ yh, ushort* __restrict__ yl)
{
    __shared__ float sdl[16][CH+4], sxc[16][CH+4], sB[16][CH+4], sC[16][CH+4], sz[16][CH+4];
    int blk = blockIdx.x;
    int dblk = blk % NDBLK; int c = (blk / NDBLK) % NCHUNK; int b = blk / (NDBLK*NCHUNK);
    int d0 = dblk * 16, tid = threadIdx.x;
    int n = tid & 15, dl = tid >> 4, d = d0 + dl;
    float Areg = -__expf(A_log[d * D_STATE + n]);
    float Dv = Dpar[d];
    int ld_c = tid & 15, ld_j0 = tid >> 4;
    int base_l = b * SEQ + c * CH;
    #pragma unroll
    for (int r = 0; r < CH/16; ++r) {
        int j = ld_j0 + r * 16;
        size_t row = (size_t)(base_l + j);
        sdl[ld_c][j] = delta[row * XZ_LD + d0 + ld_c];
        sxc[ld_c][j] = bf2f(xch[row * D_INNER + d0 + ld_c]) + bf2f(xcl[row * D_INNER + d0 + ld_c]);
        sB[ld_c][j]  = bc[row * 32 + ld_c];
        sC[ld_c][j]  = bc[row * 32 + 16 + ld_c];
        sz[ld_c][j]  = xz[row * XZ_LD + D_INNER + d0 + ld_c];
    }
    __syncthreads();
    float h = Hin[(size_t)(b * NCHUNK + c) * (D_INNER * D_STATE) + d0 * D_STATE + tid];
    for (int j = 0; j < CH; ++j) {
        float dlt = sdl[dl][j];
        float dA  = __expf(dlt * Areg);
        h = fmaf(dA, h, dlt * sB[n][j] * sxc[dl][j]);
        float p = h * sC[n][j];
        p += __shfl_xor(p, 1);
        p += __shfl_xor(p, 2);
        p += __shfl_xor(p, 4);
        p += __shfl_xor(p, 8);
        if (n == 0) {
            float y = (p + sxc[dl][j] * Dv) * silu_f(sz[dl][j]);
            ushort hh = f2bf(y);
            size_t ro = (size_t)(base_l + j) * D_INNER + d;
            yh[ro] = hh;
            yl[ro] = f2bf(y - bf2f(hh));
        }
    }
}

extern "C" void kernel_launch(void* const* d_in, const int* in_sizes, int n_in,
                              void* d_out, int out_size, void* d_ws, size_t ws_size,
                              hipStream_t stream) {
    const float* x         = (const float*)d_in[0];
    const float* in_proj_w = (const float*)d_in[1];
    const float* conv_w    = (const float*)d_in[2];
    const float* conv_b    = (const float*)d_in[3];
    const float* x_proj_w  = (const float*)d_in[4];
    const float* dt_proj_w = (const float*)d_in[5];
    const float* dt_proj_b = (const float*)d_in[6];
    const float* A_log     = (const float*)d_in[7];
    const float* D_param   = (const float*)d_in[8];
    const float* out_proj_w= (const float*)d_in[9];
    float* out = (float*)d_out;

    // x hi/lo split lives in d_out (dead until final GEMM overwrites it)
    ushort* xh = (ushort*)d_out;
    ushort* xl = xh + (size_t)M_ROWS * D_MODEL;

    char* p = (char*)d_ws;
    float*  xz   = (float*)p;                 p += (size_t)M_ROWS * XZ_LD * 4;      // 50.3 MB (delta aliases cols 0..1535 later)
    float*  bc   = (float*)p;                 p += (size_t)M_ROWS * 32 * 4;         // B/C ssm
    ushort* xch  = (ushort*)p;                p += (size_t)M_ROWS * D_INNER * 2;
    ushort* xcl  = (ushort*)p;                p += (size_t)M_ROWS * D_INNER * 2;
    ushort* drh  = (ushort*)p;                p += (size_t)M_ROWS * D_INNER * 2;    // delta_raw hi, later y hi
    ushort* drl  = (ushort*)p;                p += (size_t)M_ROWS * D_INNER * 2;    // delta_raw lo, later y lo
    char* wbase = p;
    ushort* inwh = (ushort*)p;                p += (size_t)XZ_LD   * D_MODEL * 2;
    ushort* inwl = (ushort*)p;                p += (size_t)XZ_LD   * D_MODEL * 2;
    ushort* xpwh = (ushort*)p;                p += (size_t)XPW_NPAD* D_INNER * 2;
    ushort* xpwl = (ushort*)p;                p += (size_t)XPW_NPAD* D_INNER * 2;
    ushort* dtwh = (ushort*)p;                p += (size_t)D_INNER * D_INNER * 2;
    ushort* dtwl = (ushort*)p;                p += (size_t)D_INNER * D_INNER * 2;
    ushort* opwh = (ushort*)p;                p += (size_t)D_MODEL * D_INNER * 2;
    ushort* opwl = (ushort*)p;                p += (size_t)D_MODEL * D_INNER * 2;
    // scan aux overlays in_proj/x_proj weight splits (dead before pass1 runs)
    float* Pc  = (float*)wbase;
    float* Hc  = Pc  + (size_t)BATCH * NCHUNK * D_INNER * D_STATE;
    float* Hin = Hc  + (size_t)BATCH * NCHUNK * D_INNER * D_STATE;

    float* delta = xz;   // ld XZ_LD, cols 0..1535 (x_in region, dead after conv)

    // weight/activation splits
    split4<<<3072, 256, 0, stream>>>(x, xh, xl, M_ROWS * D_MODEL / 4);
    split4<<<2304, 256, 0, stream>>>(in_proj_w, inwh, inwl, XZ_LD * D_MODEL / 4);
    split_pad_xpw<<<2496, 256, 0, stream>>>(x_proj_w, xpwh, xpwl);
    split4<<<2304, 256, 0, stream>>>(dt_proj_w, dtwh, dtwl, D_INNER * D_INNER / 4);
    split4<<<1152, 256, 0, stream>>>(out_proj_w, opwh, opwl, D_MODEL * D_INNER / 4);

    // 1) xz = x @ in_proj_w^T   (N=3072, K=768)
    gemm_mfma<0,0><<<dim3(24, 32), 256, 0, stream>>>(
        xh, xl, inwh, inwl, nullptr, xz, XZ_LD, nullptr, nullptr, XZ_LD, D_MODEL);

    // 2) x_conv = silu(conv(x_in)+cb) -> bf16 hi/lo
    conv_silu<<<6144, 256, 0, stream>>>(xz, conv_w, conv_b, xch, xcl);

    // 3) x_dbl = x_conv @ x_proj_w^T ; cols<1536 -> delta_raw hi/lo, cols 1536..1567 -> bc f32
    gemm_mfma<0,1><<<dim3(13, 32), 256, 0, stream>>>(
        xch, xcl, xpwh, xpwl, nullptr, bc, 32, drh, drl, XDBL_N, D_INNER);

    // 4) delta = softplus(delta_raw @ dt_proj_w^T + b) -> f32 into xz cols 0..1535 (ld 3072)
    gemm_mfma<1,0><<<dim3(12, 32), 256, 0, stream>>>(
        drh, drl, dtwh, dtwl, dt_proj_b, delta, XZ_LD, nullptr, nullptr, D_INNER, D_INNER);

    // 5) chunked scan
    scan_pass1<<<BATCH * NCHUNK * NDBLK, 256, 0, stream>>>(delta, bc, xch, xcl, A_log, Pc, Hc);
    scan_pass2<<<(BATCH * D_INNER * D_STATE) / 256, 256, 0, stream>>>(Pc, Hc, Hin);
    scan_pass3<<<BATCH * NCHUNK * NDBLK, 256, 0, stream>>>(
        delta, bc, xch, xcl, xz, A_log, D_param, Hin, drh, drl);   // y -> drh/drl

    // 6) out = y @ out_proj_w^T   (N=768, K=1536)
    gemm_mfma<0,0><<<dim3(6, 32), 256, 0, stream>>>(
        drh, drl, opwh, opwl, nullptr, out, D_MODEL, nullptr, nullptr, D_MODEL, D_INNER);
}

// Round 3
// 436.656 us; speedup vs baseline: 3.8114x; 1.0936x over previous
//
#include <hip/hip_runtime.h>
#include <hip/hip_bf16.h>
#include <cstdint>

#define D_MODEL 768
#define D_STATE 16
#define D_CONV  4
#define D_INNER 1536
#define BATCH   2
#define SEQ     2048
#define M_ROWS  (BATCH*SEQ)            // 4096
#define XZ_LD   (2*D_INNER)            // 3072
#define XDBL_N  (D_INNER + 2*D_STATE)  // 1568
#define XPW_NPAD 1664                  // 1568 padded to 13*128
#define NCHUNK  64
#define CH      32
#define DGRP    (D_INNER/256)          // 6

typedef __attribute__((ext_vector_type(8))) __bf16 bf16x8;
typedef __attribute__((ext_vector_type(4))) float f32x4;
typedef const __attribute__((address_space(1))) void* as1cv;
typedef __attribute__((address_space(3))) void* as3v;

#define LOG2E 1.44269504088896f

__device__ __forceinline__ ushort f2bf(float f) {
    uint32_t u = __float_as_uint(f);
    return (ushort)((u + 0x7FFFu + ((u >> 16) & 1u)) >> 16);
}
__device__ __forceinline__ float bf2f(ushort h) {
    return __uint_as_float(((uint32_t)h) << 16);
}
__device__ __forceinline__ float silu_f(float v) {
    return v / (1.f + __builtin_exp2f(-v * LOG2E));
}

// ---------------- split kernels: f32 -> bf16 hi + bf16 lo ----------------
__global__ __launch_bounds__(256) void split4(const float* __restrict__ src,
                                              ushort* __restrict__ hi, ushort* __restrict__ lo,
                                              int n4) {
    int i = blockIdx.x * 256 + threadIdx.x;
    if (i >= n4) return;
    float4 v = ((const float4*)src)[i];
    ushort4 h, l;
    h.x = f2bf(v.x); l.x = f2bf(v.x - bf2f(h.x));
    h.y = f2bf(v.y); l.y = f2bf(v.y - bf2f(h.y));
    h.z = f2bf(v.z); l.z = f2bf(v.z - bf2f(h.z));
    h.w = f2bf(v.w); l.w = f2bf(v.w - bf2f(h.w));
    ((ushort4*)hi)[i] = h;
    ((ushort4*)lo)[i] = l;
}

// x_proj_w (1568,1536) -> padded (1664,1536), rows >=1568 zero
__global__ __launch_bounds__(256) void split_pad_xpw(const float* __restrict__ src,
                                                     ushort* __restrict__ hi, ushort* __restrict__ lo) {
    int i = blockIdx.x * 256 + threadIdx.x;      // < 1664*384
    int row = i / (D_INNER/4);
    float4 v = make_float4(0.f, 0.f, 0.f, 0.f);
    if (row < XDBL_N) v = ((const float4*)src)[i];
    ushort4 h, l;
    h.x = f2bf(v.x); l.x = f2bf(v.x - bf2f(h.x));
    h.y = f2bf(v.y); l.y = f2bf(v.y - bf2f(h.y));
    h.z = f2bf(v.z); l.z = f2bf(v.z - bf2f(h.z));
    h.w = f2bf(v.w); l.w = f2bf(v.w - bf2f(h.w));
    ((ushort4*)hi)[i] = h;
    ((ushort4*)lo)[i] = l;
}

// ---------------- split-bf16 MFMA GEMM ----------------
// C[m,n] = act( sum_k A[m,k]*W[n,k] + bias[n] ),  A=(M,K) as hi/lo bf16, W=(Npad,K) hi/lo bf16.
// OM==0: write f32 to Cf (ld ldc) for col<N.
// OM==1: col<1536 -> bf16 hi/lo split to Oh/Ol (ld 1536); 1536<=col<N -> f32 to Cf (ld 32, col-1536).
template<int ACT, int OM>
__global__ __launch_bounds__(256) void gemm_mfma(
    const ushort* __restrict__ Ah, const ushort* __restrict__ Al,
    const ushort* __restrict__ Wh, const ushort* __restrict__ Wl,
    const float* __restrict__ bias,
    float* __restrict__ Cf, int ldc,
    ushort* __restrict__ Oh, ushort* __restrict__ Ol,
    int N, int K)
{
    __shared__ ushort lds[4][128*64];   // Ah, Al, Wh, Wl tiles; 64 KiB total
    const int tid = threadIdx.x, lane = tid & 63, wave = tid >> 6;
    const int bm = blockIdx.y * 128, bn = blockIdx.x * 128;
    const int wr = wave >> 1, wc = wave & 1;          // wave -> 64x64 subtile
    const int r15 = lane & 15, q = lane >> 4;
    const int xorv = (lane & 7) << 4;                  // read-side XOR swizzle
    f32x4 acc[4][4] = {};

    // staging geometry: linear LDS offset -> (row, colb); global col pre-swizzled (rule 21)
    int srowv[4], scolb[4], soff[4];
    #pragma unroll
    for (int i = 0; i < 4; ++i) {
        int off = wave*4096 + i*1024 + lane*16;
        int row = off >> 7;
        srowv[i] = row;
        scolb[i] = (off & 127) ^ ((row & 7) << 4);
        soff[i]  = wave*4096 + i*1024;                 // wave-uniform LDS base
    }

    for (int k0 = 0; k0 < K; k0 += 64) {
        if (k0) __syncthreads();
        #pragma unroll
        for (int i = 0; i < 4; ++i) {
            size_t arow = ((size_t)(bm + srowv[i]) * K + k0) * 2;
            size_t brow = ((size_t)(bn + srowv[i]) * K + k0) * 2;
            __builtin_amdgcn_global_load_lds((as1cv)((const char*)Ah + arow + scolb[i]),
                                             (as3v)((char*)lds[0] + soff[i]), 16, 0, 0);
            __builtin_amdgcn_global_load_lds((as1cv)((const char*)Al + arow + scolb[i]),
                                             (as3v)((char*)lds[1] + soff[i]), 16, 0, 0);
            __builtin_amdgcn_global_load_lds((as1cv)((const char*)Wh + brow + scolb[i]),
                                             (as3v)((char*)lds[2] + soff[i]), 16, 0, 0);
            __builtin_amdgcn_global_load_lds((as1cv)((const char*)Wl + brow + scolb[i]),
                                             (as3v)((char*)lds[3] + soff[i]), 16, 0, 0);
        }
        __syncthreads();   // drains vmcnt before use
        #pragma unroll
        for (int kk = 0; kk < 2; ++kk) {
            const int kb = kk*64 + q*16;
            bf16x8 ah[4], al[4], bh[4], bl[4];
            #pragma unroll
            for (int m = 0; m < 4; ++m) {
                int row = wr*64 + m*16 + r15;
                int sc = row*128 + (kb ^ xorv);
                ah[m] = *(const bf16x8*)((const char*)lds[0] + sc);
                al[m] = *(const bf16x8*)((const char*)lds[1] + sc);
            }
            #pragma unroll
            for (int n = 0; n < 4; ++n) {
                int row = wc*64 + n*16 + r15;
                int sc = row*128 + (kb ^ xorv);
                bh[n] = *(const bf16x8*)((const char*)lds[2] + sc);
                bl[n] = *(const bf16x8*)((const char*)lds[3] + sc);
            }
            #pragma unroll
            for (int m = 0; m < 4; ++m)
                #pragma unroll
                for (int n = 0; n < 4; ++n) {
                    acc[m][n] = __builtin_amdgcn_mfma_f32_16x16x32_bf16(ah[m], bh[n], acc[m][n], 0, 0, 0);
                    acc[m][n] = __builtin_amdgcn_mfma_f32_16x16x32_bf16(ah[m], bl[n], acc[m][n], 0, 0, 0);
                    acc[m][n] = __builtin_amdgcn_mfma_f32_16x16x32_bf16(al[m], bh[n], acc[m][n], 0, 0, 0);
                }
        }
    }

    #pragma unroll
    for (int m = 0; m < 4; ++m) {
        #pragma unroll
        for (int n = 0; n < 4; ++n) {
            int col = bn + wc*64 + n*16 + r15;
            if (col >= N) continue;
            float bv = bias ? bias[col] : 0.f;
            #pragma unroll
            for (int r = 0; r < 4; ++r) {
                int rowg = bm + wr*64 + m*16 + q*4 + r;
                float v = acc[m][n][r] + bv;
                if (ACT == 1) v = (v > 20.f) ? v : log1pf(__expf(v));
                if (OM == 0) {
                    Cf[(size_t)rowg * ldc + col] = v;
                } else {
                    if (col < D_INNER) {
                        ushort hh = f2bf(v);
                        size_t o = (size_t)rowg * D_INNER + col;
                        Oh[o] = hh;
                        Ol[o] = f2bf(v - bf2f(hh));
                    } else {
                        Cf[(size_t)rowg * 32 + (col - D_INNER)] = v;
                    }
                }
            }
        }
    }
}

// ---------------- depthwise causal conv (k=4) + bias + SiLU -> bf16 hi/lo ----------------
__global__ __launch_bounds__(256) void conv_silu(
    const float* __restrict__ xz,
    const float* __restrict__ cw, const float* __restrict__ cb,
    ushort* __restrict__ xch, ushort* __restrict__ xcl)
{
    int idx = blockIdx.x * 256 + threadIdx.x;   // over M_ROWS * 384
    int d4  = idx % (D_INNER / 4);
    int row = idx / (D_INNER / 4);
    int l = row & (SEQ - 1);
    int d = d4 * 4;
    float4 acc = make_float4(cb[d], cb[d+1], cb[d+2], cb[d+3]);
    #pragma unroll
    for (int jj = 0; jj < D_CONV; ++jj) {
        int ls = l + jj - (D_CONV - 1);
        if (ls >= 0) {
            const float4 xv = *reinterpret_cast<const float4*>(
                &xz[(size_t)(row + jj - (D_CONV - 1)) * XZ_LD + d]);
            acc.x = fmaf(xv.x, cw[(d+0)*D_CONV + jj], acc.x);
            acc.y = fmaf(xv.y, cw[(d+1)*D_CONV + jj], acc.y);
            acc.z = fmaf(xv.z, cw[(d+2)*D_CONV + jj], acc.z);
            acc.w = fmaf(xv.w, cw[(d+3)*D_CONV + jj], acc.w);
        }
    }
    acc.x = silu_f(acc.x); acc.y = silu_f(acc.y);
    acc.z = silu_f(acc.z); acc.w = silu_f(acc.w);
    ushort4 h, l4;
    h.x = f2bf(acc.x); l4.x = f2bf(acc.x - bf2f(h.x));
    h.y = f2bf(acc.y); l4.y = f2bf(acc.y - bf2f(h.y));
    h.z = f2bf(acc.z); l4.z = f2bf(acc.z - bf2f(h.z));
    h.w = f2bf(acc.w); l4.w = f2bf(acc.w - bf2f(h.w));
    size_t o = ((size_t)row * D_INNER + d) >> 2;
    ((ushort4*)xch)[o] = h;
    ((ushort4*)xcl)[o] = l4;
}

// ---------------- chunked selective scan, register-state version ----------------
// Thread owns one d-channel; 16 states in registers. B/C rows are block-uniform
// (scalarized by the compiler). No LDS, no shuffles, no barriers.

// pass1: per chunk local scan from h=0 -> Hc; P = exp(Areg * sum(dlt))
__global__ __launch_bounds__(256, 3) void scan_pass1(
    const float* __restrict__ delta,   // ld XZ_LD (aliased into xz cols 0..1535)
    const float* __restrict__ bc,      // (M_ROWS,32): B at +0, C at +16
    const ushort* __restrict__ xch, const ushort* __restrict__ xcl,
    const float* __restrict__ A_log,
    float* __restrict__ Pc, float* __restrict__ Hc)
{
    const int blk = blockIdx.x;
    const int dg = blk % DGRP;
    const int c  = (blk / DGRP) % NCHUNK;
    const int b  = blk / (DGRP * NCHUNK);
    const int d  = dg * 256 + threadIdx.x;
    const int row0 = b * SEQ + c * CH;

    float AregL2[D_STATE];
    #pragma unroll
    for (int r = 0; r < 4; ++r) {
        float4 a = *(const float4*)&A_log[d * D_STATE + r * 4];
        AregL2[r*4+0] = -__builtin_exp2f(a.x * LOG2E) * LOG2E;
        AregL2[r*4+1] = -__builtin_exp2f(a.y * LOG2E) * LOG2E;
        AregL2[r*4+2] = -__builtin_exp2f(a.z * LOG2E) * LOG2E;
        AregL2[r*4+3] = -__builtin_exp2f(a.w * LOG2E) * LOG2E;
    }

    float dl[CH], xc[CH];
    #pragma unroll
    for (int j = 0; j < CH; ++j)
        dl[j] = delta[(size_t)(row0 + j) * XZ_LD + d];
    #pragma unroll
    for (int j = 0; j < CH; ++j) {
        size_t o = (size_t)(row0 + j) * D_INNER + d;
        xc[j] = bf2f(xch[o]) + bf2f(xcl[o]);
    }

    float h[D_STATE] = {};
    float sumdlt = 0.f;
    #pragma unroll
    for (int j = 0; j < CH; ++j) {
        const float dlt = dl[j];
        const float dbx = dlt * xc[j];
        sumdlt += dlt;
        const float* brow = bc + (size_t)(row0 + j) * 32;   // block-uniform -> s_load
        #pragma unroll
        for (int n = 0; n < D_STATE; ++n)
            h[n] = fmaf(__builtin_exp2f(dlt * AregL2[n]), h[n], dbx * brow[n]);
    }

    size_t o = ((size_t)(b * NCHUNK + c) * D_INNER + d) * D_STATE;
    #pragma unroll
    for (int r = 0; r < 4; ++r) {
        ((float4*)(Hc + o))[r] = make_float4(h[r*4], h[r*4+1], h[r*4+2], h[r*4+3]);
        ((float4*)(Pc + o))[r] = make_float4(
            __builtin_exp2f(AregL2[r*4+0] * sumdlt), __builtin_exp2f(AregL2[r*4+1] * sumdlt),
            __builtin_exp2f(AregL2[r*4+2] * sumdlt), __builtin_exp2f(AregL2[r*4+3] * sumdlt));
    }
}

// pass2: cross-chunk recurrence; Hin (= h entering chunk c) written in place over Pc
__global__ __launch_bounds__(256) void scan_pass2(
    float* __restrict__ Pc, const float* __restrict__ Hc)
{
    int t = blockIdx.x * 256 + threadIdx.x;     // < BATCH * D_INNER * D_STATE
    int b = t / (D_INNER * D_STATE);
    int dn = t % (D_INNER * D_STATE);
    float h = 0.f;
    for (int c = 0; c < NCHUNK; ++c) {
        size_t o = (size_t)(b * NCHUNK + c) * (D_INNER * D_STATE) + dn;
        float P = Pc[o];
        float hc = Hc[o];
        Pc[o] = h;                 // Hin for chunk c
        h = fmaf(P, h, hc);
    }
}

// pass3: replay chunk with true h_in; y = (sum_n h*C + xc*D)*silu(z) -> bf16 hi/lo
__global__ __launch_bounds__(256, 3) void scan_pass3(
    const float* __restrict__ delta, const float* __restrict__ bc,
    const ushort* __restrict__ xch, const ushort* __restrict__ xcl,
    const float* __restrict__ xz,    // z at col +D_INNER
    const float* __restrict__ A_log, const float* __restrict__ Dpar,
    const float* __restrict__ Hin,
    ushort* __restrict__ yh, ushort* __restrict__ yl)
{
    const int blk = blockIdx.x;
    const int dg = blk % DGRP;
    const int c  = (blk / DGRP) % NCHUNK;
    const int b  = blk / (DGRP * NCHUNK);
    const int d  = dg * 256 + threadIdx.x;
    const int row0 = b * SEQ + c * CH;

    float AregL2[D_STATE];
    #pragma unroll
    for (int r = 0; r < 4; ++r) {
        float4 a = *(const float4*)&A_log[d * D_STATE + r * 4];
        AregL2[r*4+0] = -__builtin_exp2f(a.x * LOG2E) * LOG2E;
        AregL2[r*4+1] = -__builtin_exp2f(a.y * LOG2E) * LOG2E;
        AregL2[r*4+2] = -__builtin_exp2f(a.z * LOG2E) * LOG2E;
        AregL2[r*4+3] = -__builtin_exp2f(a.w * LOG2E) * LOG2E;
    }
    const float Dv = Dpar[d];

    float dl[CH], xc[CH];
    #pragma unroll
    for (int j = 0; j < CH; ++j)
        dl[j] = delta[(size_t)(row0 + j) * XZ_LD + d];
    #pragma unroll
    for (int j = 0; j < CH; ++j) {
        size_t o = (size_t)(row0 + j) * D_INNER + d;
        xc[j] = bf2f(xch[o]) + bf2f(xcl[o]);
    }

    float h[D_STATE];
    {
        size_t o = ((size_t)(b * NCHUNK + c) * D_INNER + d) * D_STATE;
        #pragma unroll
        for (int r = 0; r < 4; ++r) {
            float4 v = ((const float4*)(Hin + o))[r];
            h[r*4] = v.x; h[r*4+1] = v.y; h[r*4+2] = v.z; h[r*4+3] = v.w;
        }
    }

    #pragma unroll
    for (int j = 0; j < CH; ++j) {
        const float dlt = dl[j];
        const float dbx = dlt * xc[j];
        const float* brow = bc + (size_t)(row0 + j) * 32;   // block-uniform -> s_load
        #pragma unroll
        for (int n = 0; n < D_STATE; ++n)
            h[n] = fmaf(__builtin_exp2f(dlt * AregL2[n]), h[n], dbx * brow[n]);
        float p0 = 0.f, p1 = 0.f, p2 = 0.f, p3 = 0.f;
        #pragma unroll
        for (int n = 0; n < 4; ++n) {
            p0 = fmaf(h[n],      brow[16 + n],      p0);
            p1 = fmaf(h[4 + n],  brow[16 + 4 + n],  p1);
            p2 = fmaf(h[8 + n],  brow[16 + 8 + n],  p2);
            p3 = fmaf(h[12 + n], brow[16 + 12 + n], p3);
        }
        const float zv = xz[(size_t)(row0 + j) * XZ_LD + D_INNER + d];
        const float y = ((p0 + p1) + (p2 + p3) + xc[j] * Dv) * silu_f(zv);
        const ushort hh = f2bf(y);
        size_t ro = (size_t)(row0 + j) * D_INNER + d;
        yh[ro] = hh;
        yl[ro] = f2bf(y - bf2f(hh));
    }
}

extern "C" void kernel_launch(void* const* d_in, const int* in_sizes, int n_in,
                              void* d_out, int out_size, void* d_ws, size_t ws_size,
                              hipStream_t stream) {
    const float* x         = (const float*)d_in[0];
    const float* in_proj_w = (const float*)d_in[1];
    const float* conv_w    = (const float*)d_in[2];
    const float* conv_b    = (const float*)d_in[3];
    const float* x_proj_w  = (const float*)d_in[4];
    const float* dt_proj_w = (const float*)d_in[5];
    const float* dt_proj_b = (const float*)d_in[6];
    const float* A_log     = (const float*)d_in[7];
    const float* D_param   = (const float*)d_in[8];
    const float* out_proj_w= (const float*)d_in[9];
    float* out = (float*)d_out;

    // x hi/lo split lives in d_out (dead until final GEMM overwrites it)
    ushort* xh = (ushort*)d_out;
    ushort* xl = xh + (size_t)M_ROWS * D_MODEL;

    char* p = (char*)d_ws;
    float*  xz   = (float*)p;                 p += (size_t)M_ROWS * XZ_LD * 4;      // 50.3 MB (delta aliases cols 0..1535 later)
    float*  bc   = (float*)p;                 p += (size_t)M_ROWS * 32 * 4;         // B/C ssm
    ushort* xch  = (ushort*)p;                p += (size_t)M_ROWS * D_INNER * 2;
    ushort* xcl  = (ushort*)p;                p += (size_t)M_ROWS * D_INNER * 2;
    ushort* drh  = (ushort*)p;                p += (size_t)M_ROWS * D_INNER * 2;    // delta_raw hi, later y hi
    ushort* drl  = (ushort*)p;                p += (size_t)M_ROWS * D_INNER * 2;    // delta_raw lo, later y lo
    char* wbase = p;
    ushort* inwh = (ushort*)p;                p += (size_t)XZ_LD   * D_MODEL * 2;
    ushort* inwl = (ushort*)p;                p += (size_t)XZ_LD   * D_MODEL * 2;
    ushort* xpwh = (ushort*)p;                p += (size_t)XPW_NPAD* D_INNER * 2;
    ushort* xpwl = (ushort*)p;                p += (size_t)XPW_NPAD* D_INNER * 2;
    ushort* dtwh = (ushort*)p;                p += (size_t)D_INNER * D_INNER * 2;
    ushort* dtwl = (ushort*)p;                p += (size_t)D_INNER * D_INNER * 2;
    ushort* opwh = (ushort*)p;                p += (size_t)D_MODEL * D_INNER * 2;
    ushort* opwl = (ushort*)p;                p += (size_t)D_MODEL * D_INNER * 2;
    // scan aux (Pc, Hc: 12.6 MB each) overlays inwh..dtwl (24.3 MB+, dead after
    // GEMM4); opwh/opwl (needed by GEMM6 after the scan) start at +29.1 MB from
    // wbase, Pc+Hc end at +25.2 MB -> safe.
    float* Pc  = (float*)wbase;
    float* Hc  = Pc + (size_t)BATCH * NCHUNK * D_INNER * D_STATE;

    float* delta = xz;   // ld XZ_LD, cols 0..1535 (x_in region, dead after conv)

    // weight/activation splits
    split4<<<3072, 256, 0, stream>>>(x, xh, xl, M_ROWS * D_MODEL / 4);
    split4<<<2304, 256, 0, stream>>>(in_proj_w, inwh, inwl, XZ_LD * D_MODEL / 4);
    split_pad_xpw<<<2496, 256, 0, stream>>>(x_proj_w, xpwh, xpwl);
    split4<<<2304, 256, 0, stream>>>(dt_proj_w, dtwh, dtwl, D_INNER * D_INNER / 4);
    split4<<<1152, 256, 0, stream>>>(out_proj_w, opwh, opwl, D_MODEL * D_INNER / 4);

    // 1) xz = x @ in_proj_w^T   (N=3072, K=768)
    gemm_mfma<0,0><<<dim3(24, 32), 256, 0, stream>>>(
        xh, xl, inwh, inwl, nullptr, xz, XZ_LD, nullptr, nullptr, XZ_LD, D_MODEL);

    // 2) x_conv = silu(conv(x_in)+cb) -> bf16 hi/lo
    conv_silu<<<6144, 256, 0, stream>>>(xz, conv_w, conv_b, xch, xcl);

    // 3) x_dbl = x_conv @ x_proj_w^T ; cols<1536 -> delta_raw hi/lo, cols 1536..1567 -> bc f32
    gemm_mfma<0,1><<<dim3(13, 32), 256, 0, stream>>>(
        xch, xcl, xpwh, xpwl, nullptr, bc, 32, drh, drl, XDBL_N, D_INNER);

    // 4) delta = softplus(delta_raw @ dt_proj_w^T + b) -> f32 into xz cols 0..1535 (ld 3072)
    gemm_mfma<1,0><<<dim3(12, 32), 256, 0, stream>>>(
        drh, drl, dtwh, dtwl, dt_proj_b, delta, XZ_LD, nullptr, nullptr, D_INNER, D_INNER);

    // 5) chunked scan (register-state, no LDS)
    scan_pass1<<<BATCH * NCHUNK * DGRP, 256, 0, stream>>>(delta, bc, xch, xcl, A_log, Pc, Hc);
    scan_pass2<<<(BATCH * D_INNER * D_STATE) / 256, 256, 0, stream>>>(Pc, Hc);
    scan_pass3<<<BATCH * NCHUNK * DGRP, 256, 0, stream>>>(
        delta, bc, xch, xcl, xz, A_log, D_param, Pc, drh, drl);   // y -> drh/drl

    // 6) out = y @ out_proj_w^T   (N=768, K=1536)
    gemm_mfma<0,0><<<dim3(6, 32), 256, 0, stream>>>(
        drh, drl, opwh, opwl, nullptr, out, D_MODEL, nullptr, nullptr, D_MODEL, D_INNER);
}

// Round 4
// 404.239 us; speedup vs baseline: 4.1171x; 1.0802x over previous
//
#include <hip/hip_runtime.h>
#include <hip/hip_bf16.h>
#include <hip/hip_fp16.h>
#include <cstdint>

#define D_MODEL 768
#define D_STATE 16
#define D_CONV  4
#define D_INNER 1536
#define BATCH   2
#define SEQ     2048
#define M_ROWS  (BATCH*SEQ)            // 4096
#define XZ_LD   (2*D_INNER)            // 3072
#define XDBL_N  (D_INNER + 2*D_STATE)  // 1568
#define WFULL_R 1664                   // 1568 padded to 13*128
#define NCHUNK  64
#define CH      32
#define DGRP    (D_INNER/256)          // 6

typedef __attribute__((ext_vector_type(8))) _Float16 f16x8;
typedef __attribute__((ext_vector_type(4))) float f32x4;
typedef const __attribute__((address_space(1))) void* as1cv;
typedef __attribute__((address_space(3))) void* as3v;

#define LOG2E 1.44269504088896f

__device__ __forceinline__ ushort f2h(float f) { return __half_as_ushort(__float2half(f)); }
__device__ __forceinline__ float h2f(ushort u) { return __half2float(__ushort_as_half(u)); }
__device__ __forceinline__ float silu_f(float v) {
    return v / (1.f + __builtin_exp2f(-v * LOG2E));
}

// ---------------- prep kernels ----------------
// f32 -> fp16 hi + fp16 lo (activation-side split; hi+lo ~ 21 mantissa bits)
__global__ __launch_bounds__(256) void split4_h(const float* __restrict__ src,
                                                ushort* __restrict__ hi, ushort* __restrict__ lo,
                                                int n4) {
    int i = blockIdx.x * 256 + threadIdx.x;
    if (i >= n4) return;
    float4 v = ((const float4*)src)[i];
    ushort4 h, l;
    h.x = f2h(v.x); l.x = f2h(v.x - h2f(h.x));
    h.y = f2h(v.y); l.y = f2h(v.y - h2f(h.y));
    h.z = f2h(v.z); l.z = f2h(v.z - h2f(h.z));
    h.w = f2h(v.w); l.w = f2h(v.w - h2f(h.w));
    ((ushort4*)hi)[i] = h;
    ((ushort4*)lo)[i] = l;
}

// f32 -> single fp16 (weight side)
__global__ __launch_bounds__(256) void convh4(const float* __restrict__ src,
                                              ushort* __restrict__ dst, int n4) {
    int i = blockIdx.x * 256 + threadIdx.x;
    if (i >= n4) return;
    float4 v = ((const float4*)src)[i];
    ushort4 h;
    h.x = f2h(v.x); h.y = f2h(v.y); h.z = f2h(v.z); h.w = f2h(v.w);
    ((ushort4*)dst)[i] = h;
}

// transpose 1536x1536 f32 -> fp16: dst[j][i] = src[i][j]
__global__ __launch_bounds__(256) void transpose_h(const float* __restrict__ src,
                                                   ushort* __restrict__ dst) {
    __shared__ ushort t[64][65];
    const int bx = blockIdx.x * 64;   // src col block
    const int by = blockIdx.y * 64;   // src row block
    const int c = threadIdx.x & 63, r0 = threadIdx.x >> 6;
    #pragma unroll
    for (int i = 0; i < 16; ++i) {
        int r = r0 + i * 4;
        t[c][r] = f2h(src[(size_t)(by + r) * D_INNER + bx + c]);
    }
    __syncthreads();
    #pragma unroll
    for (int i = 0; i < 16; ++i) {
        int rr = r0 + i * 4;
        dst[(size_t)(bx + rr) * D_INNER + by + c] = t[rr][c];
    }
}

// Wfull rows 1536..1663: rows <1568 = fp16(xpw row), rows >=1568 = 0
__global__ __launch_bounds__(256) void bc_pad(const float* __restrict__ xpw,
                                              ushort* __restrict__ Wfull) {
    int i = blockIdx.x * 256 + threadIdx.x;   // < 128*1536
    int row = 1536 + i / D_INNER, col = i % D_INNER;
    float v = (row < XDBL_N) ? xpw[(size_t)row * D_INNER + col] : 0.f;
    Wfull[(size_t)row * D_INNER + col] = f2h(v);
}

// ---------------- fp16 2-product MFMA GEMM ----------------
// C[m,n] = sum_k (Ah+Al)[m,k]*Wh[n,k]  (+bias, +epilogue per OM)
// OM=0: f32 -> Cf (ld ldc)
// OM=1: col<1536 -> f32 Cf (ld 1536, x_in); col>=1536 -> fp16 silu -> Oh (ld 1536, gated z)
// OM=2: col<1536 -> softplus(v+bias) f32 -> Cf (ld 1536, delta); 1536<=col<1568 -> f32 Cf2 (ld 32, bc)
// OM=3: fp16 -> Oh (ld 1536, Wcomb rows)
template<int OM>
__global__ __launch_bounds__(256, 3) void gemm_h(
    const ushort* __restrict__ Ah, const ushort* __restrict__ Al,
    const ushort* __restrict__ Wh,
    const float* __restrict__ bias,
    float* __restrict__ Cf, float* __restrict__ Cf2, int ldc,
    ushort* __restrict__ Oh,
    int N, int K)
{
    __shared__ ushort lds[3][128*64];   // Ah, Al, Wh tiles; 48 KiB
    const int tid = threadIdx.x, lane = tid & 63, wave = tid >> 6;
    // XCD swizzle (all grids are multiples of 8), bm-chunked per XCD
    const int gx = gridDim.x, nwg = gx * gridDim.y;
    const int lid = blockIdx.y * gx + blockIdx.x;
    const int swz = (lid & 7) * (nwg >> 3) + (lid >> 3);
    const int bm = (swz / gx) * 128, bn = (swz % gx) * 128;
    const int wr = wave >> 1, wc = wave & 1;          // wave -> 64x64 subtile
    const int r15 = lane & 15, q = lane >> 4;
    const int xorv = (lane & 7) << 4;                  // read-side XOR swizzle
    f32x4 acc[4][4] = {};

    // staging geometry: linear LDS offset -> (row, colb); global col pre-swizzled (rule 21)
    int srowv[4], scolb[4], soff[4];
    #pragma unroll
    for (int i = 0; i < 4; ++i) {
        int off = wave*4096 + i*1024 + lane*16;
        int row = off >> 7;
        srowv[i] = row;
        scolb[i] = (off & 127) ^ ((row & 7) << 4);
        soff[i]  = wave*4096 + i*1024;                 // wave-uniform LDS base
    }

    for (int k0 = 0; k0 < K; k0 += 64) {
        if (k0) __syncthreads();
        #pragma unroll
        for (int i = 0; i < 4; ++i) {
            size_t arow = ((size_t)(bm + srowv[i]) * K + k0) * 2;
            size_t brow = ((size_t)(bn + srowv[i]) * K + k0) * 2;
            __builtin_amdgcn_global_load_lds((as1cv)((const char*)Ah + arow + scolb[i]),
                                             (as3v)((char*)lds[0] + soff[i]), 16, 0, 0);
            __builtin_amdgcn_global_load_lds((as1cv)((const char*)Al + arow + scolb[i]),
                                             (as3v)((char*)lds[1] + soff[i]), 16, 0, 0);
            __builtin_amdgcn_global_load_lds((as1cv)((const char*)Wh + brow + scolb[i]),
                                             (as3v)((char*)lds[2] + soff[i]), 16, 0, 0);
        }
        __syncthreads();   // drains vmcnt before use
        #pragma unroll
        for (int kk = 0; kk < 2; ++kk) {
            const int kb = kk*64 + q*16;
            f16x8 ah[4], al[4], wh[4];
            #pragma unroll
            for (int m = 0; m < 4; ++m) {
                int row = wr*64 + m*16 + r15;
                int sc = row*128 + (kb ^ xorv);
                ah[m] = *(const f16x8*)((const char*)lds[0] + sc);
                al[m] = *(const f16x8*)((const char*)lds[1] + sc);
            }
            #pragma unroll
            for (int n = 0; n < 4; ++n) {
                int row = wc*64 + n*16 + r15;
                int sc = row*128 + (kb ^ xorv);
                wh[n] = *(const f16x8*)((const char*)lds[2] + sc);
            }
            #pragma unroll
            for (int m = 0; m < 4; ++m)
                #pragma unroll
                for (int n = 0; n < 4; ++n) {
                    acc[m][n] = __builtin_amdgcn_mfma_f32_16x16x32_f16(ah[m], wh[n], acc[m][n], 0, 0, 0);
                    acc[m][n] = __builtin_amdgcn_mfma_f32_16x16x32_f16(al[m], wh[n], acc[m][n], 0, 0, 0);
                }
        }
    }

    #pragma unroll
    for (int m = 0; m < 4; ++m) {
        #pragma unroll
        for (int n = 0; n < 4; ++n) {
            int col = bn + wc*64 + n*16 + r15;
            if (col >= N) continue;
            #pragma unroll
            for (int r = 0; r < 4; ++r) {
                int rowg = bm + wr*64 + m*16 + q*4 + r;
                float v = acc[m][n][r];
                if constexpr (OM == 0) {
                    Cf[(size_t)rowg * ldc + col] = v;
                } else if constexpr (OM == 1) {
                    if (col < D_INNER) Cf[(size_t)rowg * D_INNER + col] = v;
                    else Oh[(size_t)rowg * D_INNER + (col - D_INNER)] = f2h(silu_f(v));
                } else if constexpr (OM == 2) {
                    if (col < D_INNER) {
                        float t = v + bias[col];
                        Cf[(size_t)rowg * D_INNER + col] = (t > 20.f) ? t : log1pf(__expf(t));
                    } else {
                        Cf2[(size_t)rowg * 32 + (col - D_INNER)] = v;
                    }
                } else {   // OM == 3
                    Oh[(size_t)rowg * D_INNER + col] = f2h(v);
                }
            }
        }
    }
}

// ---------------- depthwise causal conv (k=4) + bias + SiLU -> fp16 hi/lo ----------------
__global__ __launch_bounds__(256) void conv_silu(
    const float* __restrict__ xin,  // (M_ROWS, 1536) f32
    const float* __restrict__ cw, const float* __restrict__ cb,
    ushort* __restrict__ xch, ushort* __restrict__ xcl)
{
    int idx = blockIdx.x * 256 + threadIdx.x;   // over M_ROWS * 384
    int d4  = idx % (D_INNER / 4);
    int row = idx / (D_INNER / 4);
    int l = row & (SEQ - 1);
    int d = d4 * 4;
    float4 acc = make_float4(cb[d], cb[d+1], cb[d+2], cb[d+3]);
    #pragma unroll
    for (int jj = 0; jj < D_CONV; ++jj) {
        int ls = l + jj - (D_CONV - 1);
        if (ls >= 0) {
            const float4 xv = *reinterpret_cast<const float4*>(
                &xin[(size_t)(row + jj - (D_CONV - 1)) * D_INNER + d]);
            acc.x = fmaf(xv.x, cw[(d+0)*D_CONV + jj], acc.x);
            acc.y = fmaf(xv.y, cw[(d+1)*D_CONV + jj], acc.y);
            acc.z = fmaf(xv.z, cw[(d+2)*D_CONV + jj], acc.z);
            acc.w = fmaf(xv.w, cw[(d+3)*D_CONV + jj], acc.w);
        }
    }
    acc.x = silu_f(acc.x); acc.y = silu_f(acc.y);
    acc.z = silu_f(acc.z); acc.w = silu_f(acc.w);
    ushort4 h, l4;
    h.x = f2h(acc.x); l4.x = f2h(acc.x - h2f(h.x));
    h.y = f2h(acc.y); l4.y = f2h(acc.y - h2f(h.y));
    h.z = f2h(acc.z); l4.z = f2h(acc.z - h2f(h.z));
    h.w = f2h(acc.w); l4.w = f2h(acc.w - h2f(h.w));
    size_t o = ((size_t)row * D_INNER + d) >> 2;
    ((ushort4*)xch)[o] = h;
    ((ushort4*)xcl)[o] = l4;
}

// ---------------- chunked selective scan, register-state ----------------
__global__ __launch_bounds__(256, 3) void scan_pass1(
    const float* __restrict__ delta,   // (M_ROWS,1536) f32
    const float* __restrict__ bc,      // (M_ROWS,32): B at +0, C at +16
    const ushort* __restrict__ xch, const ushort* __restrict__ xcl,
    const float* __restrict__ A_log,
    float* __restrict__ Pc, float* __restrict__ Hc)
{
    const int blk = blockIdx.x;
    const int dg = blk % DGRP;
    const int c  = (blk / DGRP) % NCHUNK;
    const int b  = blk / (DGRP * NCHUNK);
    const int d  = dg * 256 + threadIdx.x;
    const int row0 = b * SEQ + c * CH;

    float AregL2[D_STATE];
    #pragma unroll
    for (int r = 0; r < 4; ++r) {
        float4 a = *(const float4*)&A_log[d * D_STATE + r * 4];
        AregL2[r*4+0] = -__builtin_exp2f(a.x * LOG2E) * LOG2E;
        AregL2[r*4+1] = -__builtin_exp2f(a.y * LOG2E) * LOG2E;
        AregL2[r*4+2] = -__builtin_exp2f(a.z * LOG2E) * LOG2E;
        AregL2[r*4+3] = -__builtin_exp2f(a.w * LOG2E) * LOG2E;
    }

    float dl[CH], xc[CH];
    #pragma unroll
    for (int j = 0; j < CH; ++j)
        dl[j] = delta[(size_t)(row0 + j) * D_INNER + d];
    #pragma unroll
    for (int j = 0; j < CH; ++j) {
        size_t o = (size_t)(row0 + j) * D_INNER + d;
        xc[j] = h2f(xch[o]) + h2f(xcl[o]);
    }

    float h[D_STATE] = {};
    float sumdlt = 0.f;
    #pragma unroll
    for (int j = 0; j < CH; ++j) {
        const float dlt = dl[j];
        const float dbx = dlt * xc[j];
        sumdlt += dlt;
        const float* brow = bc + (size_t)(row0 + j) * 32;   // block-uniform -> s_load
        #pragma unroll
        for (int n = 0; n < D_STATE; ++n)
            h[n] = fmaf(__builtin_exp2f(dlt * AregL2[n]), h[n], dbx * brow[n]);
    }

    size_t o = ((size_t)(b * NCHUNK + c) * D_INNER + d) * D_STATE;
    #pragma unroll
    for (int r = 0; r < 4; ++r) {
        ((float4*)(Hc + o))[r] = make_float4(h[r*4], h[r*4+1], h[r*4+2], h[r*4+3]);
        ((float4*)(Pc + o))[r] = make_float4(
            __builtin_exp2f(AregL2[r*4+0] * sumdlt), __builtin_exp2f(AregL2[r*4+1] * sumdlt),
            __builtin_exp2f(AregL2[r*4+2] * sumdlt), __builtin_exp2f(AregL2[r*4+3] * sumdlt));
    }
}

__global__ __launch_bounds__(256) void scan_pass2(
    float* __restrict__ Pc, const float* __restrict__ Hc)
{
    int t = blockIdx.x * 256 + threadIdx.x;     // < BATCH * D_INNER * D_STATE
    int b = t / (D_INNER * D_STATE);
    int dn = t % (D_INNER * D_STATE);
    float h = 0.f;
    for (int c = 0; c < NCHUNK; ++c) {
        size_t o = (size_t)(b * NCHUNK + c) * (D_INNER * D_STATE) + dn;
        float P = Pc[o];
        float hc = Hc[o];
        Pc[o] = h;                 // Hin for chunk c
        h = fmaf(P, h, hc);
    }
}

// pass3: replay with true h_in; y = (sum_n h*C + xc*D)*gate -> fp16 hi/lo IN-PLACE over xch/xcl
__global__ __launch_bounds__(256, 3) void scan_pass3(
    const float* __restrict__ delta, const float* __restrict__ bc,
    ushort* xch, ushort* xcl,          // read xc, then overwritten with y (same elements)
    const ushort* __restrict__ zg,     // gated z = fp16(silu(z))
    const float* __restrict__ A_log, const float* __restrict__ Dpar,
    const float* __restrict__ Hin)
{
    const int blk = blockIdx.x;
    const int dg = blk % DGRP;
    const int c  = (blk / DGRP) % NCHUNK;
    const int b  = blk / (DGRP * NCHUNK);
    const int d  = dg * 256 + threadIdx.x;
    const int row0 = b * SEQ + c * CH;

    float AregL2[D_STATE];
    #pragma unroll
    for (int r = 0; r < 4; ++r) {
        float4 a = *(const float4*)&A_log[d * D_STATE + r * 4];
        AregL2[r*4+0] = -__builtin_exp2f(a.x * LOG2E) * LOG2E;
        AregL2[r*4+1] = -__builtin_exp2f(a.y * LOG2E) * LOG2E;
        AregL2[r*4+2] = -__builtin_exp2f(a.z * LOG2E) * LOG2E;
        AregL2[r*4+3] = -__builtin_exp2f(a.w * LOG2E) * LOG2E;
    }
    const float Dv = Dpar[d];

    float dl[CH], xc[CH];
    #pragma unroll
    for (int j = 0; j < CH; ++j)
        dl[j] = delta[(size_t)(row0 + j) * D_INNER + d];
    #pragma unroll
    for (int j = 0; j < CH; ++j) {
        size_t o = (size_t)(row0 + j) * D_INNER + d;
        xc[j] = h2f(xch[o]) + h2f(xcl[o]);
    }

    float h[D_STATE];
    {
        size_t o = ((size_t)(b * NCHUNK + c) * D_INNER + d) * D_STATE;
        #pragma unroll
        for (int r = 0; r < 4; ++r) {
            float4 v = ((const float4*)(Hin + o))[r];
            h[r*4] = v.x; h[r*4+1] = v.y; h[r*4+2] = v.z; h[r*4+3] = v.w;
        }
    }

    #pragma unroll
    for (int j = 0; j < CH; ++j) {
        const float dlt = dl[j];
        const float dbx = dlt * xc[j];
        const float* brow = bc + (size_t)(row0 + j) * 32;   // block-uniform -> s_load
        #pragma unroll
        for (int n = 0; n < D_STATE; ++n)
            h[n] = fmaf(__builtin_exp2f(dlt * AregL2[n]), h[n], dbx * brow[n]);
        float p0 = 0.f, p1 = 0.f, p2 = 0.f, p3 = 0.f;
        #pragma unroll
        for (int n = 0; n < 4; ++n) {
            p0 = fmaf(h[n],      brow[16 + n],      p0);
            p1 = fmaf(h[4 + n],  brow[16 + 4 + n],  p1);
            p2 = fmaf(h[8 + n],  brow[16 + 8 + n],  p2);
            p3 = fmaf(h[12 + n], brow[16 + 12 + n], p3);
        }
        size_t ro = (size_t)(row0 + j) * D_INNER + d;
        const float gate = h2f(zg[ro]);
        const float y = ((p0 + p1) + (p2 + p3) + xc[j] * Dv) * gate;
        const ushort hh = f2h(y);
        xch[ro] = hh;
        xcl[ro] = f2h(y - h2f(hh));
    }
}

extern "C" void kernel_launch(void* const* d_in, const int* in_sizes, int n_in,
                              void* d_out, int out_size, void* d_ws, size_t ws_size,
                              hipStream_t stream) {
    const float* x         = (const float*)d_in[0];
    const float* in_proj_w = (const float*)d_in[1];
    const float* conv_w    = (const float*)d_in[2];
    const float* conv_b    = (const float*)d_in[3];
    const float* x_proj_w  = (const float*)d_in[4];
    const float* dt_proj_w = (const float*)d_in[5];
    const float* dt_proj_b = (const float*)d_in[6];
    const float* A_log     = (const float*)d_in[7];
    const float* D_param   = (const float*)d_in[8];
    const float* out_proj_w= (const float*)d_in[9];
    float* out = (float*)d_out;

    // x hi/lo fp16 lives in d_out (12.58 MB, exactly fits; dead once GEMM1 ran)
    ushort* xh = (ushort*)d_out;
    ushort* xl = xh + (size_t)M_ROWS * D_MODEL;

    char* p = (char*)d_ws;
    float*  xin  = (float*)p;   p += (size_t)M_ROWS * D_INNER * 4;   // x_in f32, later delta (aliased)
    ushort* zg   = (ushort*)p;  p += (size_t)M_ROWS * D_INNER * 2;   // silu(z) fp16
    float*  bc   = (float*)p;   p += (size_t)M_ROWS * 32 * 4;        // B/C ssm f32
    ushort* xch  = (ushort*)p;  p += (size_t)M_ROWS * D_INNER * 2;   // x_conv hi, later y hi
    ushort* xcl  = (ushort*)p;  p += (size_t)M_ROWS * D_INNER * 2;   // x_conv lo, later y lo
    ushort* inwh = (ushort*)p;  p += (size_t)XZ_LD * D_MODEL * 2;    // in_proj fp16
    ushort* Wfull= (ushort*)p;  p += (size_t)WFULL_R * D_INNER * 2;  // [Wcomb(1536); xpw_bc(32); pad(96)]
    ushort* xpwT = (ushort*)p;  p += (size_t)D_INNER * D_INNER * 2;  // xpw_delta^T fp16
    ushort* dtwh = (ushort*)p;  p += (size_t)D_INNER * D_INNER * 2;
    ushort* dtwl = (ushort*)p;  p += (size_t)D_INNER * D_INNER * 2;
    ushort* opwh = (ushort*)p;  p += (size_t)D_MODEL * D_INNER * 2;
    float*  Pc   = (float*)p;   p += (size_t)BATCH * NCHUNK * D_INNER * D_STATE * 4;
    float*  Hc   = (float*)p;   p += (size_t)BATCH * NCHUNK * D_INNER * D_STATE * 4;
    // total ~115 MB

    float* delta = xin;   // delta overwrites x_in (dead after conv)

    // ---- prep ----
    split4_h<<<3072, 256, 0, stream>>>(x, xh, xl, M_ROWS * D_MODEL / 4);
    convh4  <<<2304, 256, 0, stream>>>(in_proj_w, inwh, XZ_LD * D_MODEL / 4);
    transpose_h<<<dim3(24,24), 256, 0, stream>>>(x_proj_w, xpwT);
    bc_pad  <<<768, 256, 0, stream>>>(x_proj_w, Wfull);
    split4_h<<<2304, 256, 0, stream>>>(dt_proj_w, dtwh, dtwl, D_INNER * D_INNER / 4);
    convh4  <<<1152, 256, 0, stream>>>(out_proj_w, opwh, D_MODEL * D_INNER / 4);

    // ---- W_comb = dt_proj_w @ xpw_delta  (rows 0..1535 of Wfull) ----
    gemm_h<3><<<dim3(12,12), 256, 0, stream>>>(
        dtwh, dtwl, xpwT, nullptr, nullptr, nullptr, D_INNER, Wfull, D_INNER, D_INNER);

    // ---- 1) xz = x @ in_proj^T: x_in f32 + zg=silu(z) fp16 ----
    gemm_h<1><<<dim3(24,32), 256, 0, stream>>>(
        xh, xl, inwh, nullptr, xin, nullptr, D_INNER, zg, XZ_LD, D_MODEL);

    // ---- 2) x_conv ----
    conv_silu<<<6144, 256, 0, stream>>>(xin, conv_w, conv_b, xch, xcl);

    // ---- 3+4 fused) delta = softplus(xc @ Wcomb^T + b); bc cols from xpw rows ----
    gemm_h<2><<<dim3(13,32), 256, 0, stream>>>(
        xch, xcl, Wfull, dt_proj_b, delta, bc, D_INNER, nullptr, XDBL_N, D_INNER);

    // ---- 5) chunked scan ----
    scan_pass1<<<BATCH * NCHUNK * DGRP, 256, 0, stream>>>(delta, bc, xch, xcl, A_log, Pc, Hc);
    scan_pass2<<<(BATCH * D_INNER * D_STATE) / 256, 256, 0, stream>>>(Pc, Hc);
    scan_pass3<<<BATCH * NCHUNK * DGRP, 256, 0, stream>>>(
        delta, bc, xch, xcl, zg, A_log, D_param, Pc);   // y -> xch/xcl in place

    // ---- 6) out = y @ out_proj^T ----
    gemm_h<0><<<dim3(6,32), 256, 0, stream>>>(
        xch, xcl, opwh, nullptr, out, nullptr, D_MODEL, nullptr, D_MODEL, D_INNER);
}

// Round 5
// 325.053 us; speedup vs baseline: 5.1200x; 1.2436x over previous
//
#include <hip/hip_runtime.h>
#include <hip/hip_bf16.h>
#include <hip/hip_fp16.h>
#include <cstdint>

#define D_MODEL 768
#define D_STATE 16
#define D_CONV  4
#define D_INNER 1536
#define BATCH   2
#define SEQ     2048
#define M_ROWS  (BATCH*SEQ)            // 4096
#define XZ_LD   (2*D_INNER)            // 3072
#define XDBL_N  (D_INNER + 2*D_STATE)  // 1568
#define WFULL_R 1664                   // 1568 padded to 13*128
#define NCHUNK  128
#define CH      16
#define DGRP    (D_INNER/256)          // 6

typedef __attribute__((ext_vector_type(8))) _Float16 f16x8;
typedef __attribute__((ext_vector_type(4))) float f32x4;
typedef __attribute__((ext_vector_type(8))) ushort ushort8v;
typedef const __attribute__((address_space(1))) void* as1cv;
typedef __attribute__((address_space(3))) void* as3v;

#define LOG2E 1.44269504088896f

__device__ __forceinline__ ushort f2h(float f) { return __half_as_ushort(__float2half(f)); }
__device__ __forceinline__ float h2f(ushort u) { return __half2float(__ushort_as_half(u)); }
__device__ __forceinline__ float silu_f(float v) {
    return v / (1.f + __builtin_exp2f(-v * LOG2E));
}

// ---------------- prep kernels ----------------
__global__ __launch_bounds__(256) void split4_h(const float* __restrict__ src,
                                                ushort* __restrict__ hi, ushort* __restrict__ lo,
                                                int n4) {
    int i = blockIdx.x * 256 + threadIdx.x;
    if (i >= n4) return;
    float4 v = ((const float4*)src)[i];
    ushort4 h, l;
    h.x = f2h(v.x); l.x = f2h(v.x - h2f(h.x));
    h.y = f2h(v.y); l.y = f2h(v.y - h2f(h.y));
    h.z = f2h(v.z); l.z = f2h(v.z - h2f(h.z));
    h.w = f2h(v.w); l.w = f2h(v.w - h2f(h.w));
    ((ushort4*)hi)[i] = h;
    ((ushort4*)lo)[i] = l;
}

__global__ __launch_bounds__(256) void convh4(const float* __restrict__ src,
                                              ushort* __restrict__ dst, int n4) {
    int i = blockIdx.x * 256 + threadIdx.x;
    if (i >= n4) return;
    float4 v = ((const float4*)src)[i];
    ushort4 h;
    h.x = f2h(v.x); h.y = f2h(v.y); h.z = f2h(v.z); h.w = f2h(v.w);
    ((ushort4*)dst)[i] = h;
}

// transpose 1536x1536 f32 -> fp16: dst[j][i] = src[i][j]
__global__ __launch_bounds__(256) void transpose_h(const float* __restrict__ src,
                                                   ushort* __restrict__ dst) {
    __shared__ ushort t[64][65];
    const int bx = blockIdx.x * 64;
    const int by = blockIdx.y * 64;
    const int c = threadIdx.x & 63, r0 = threadIdx.x >> 6;
    #pragma unroll
    for (int i = 0; i < 16; ++i) {
        int r = r0 + i * 4;
        t[c][r] = f2h(src[(size_t)(by + r) * D_INNER + bx + c]);
    }
    __syncthreads();
    #pragma unroll
    for (int i = 0; i < 16; ++i) {
        int rr = r0 + i * 4;
        dst[(size_t)(bx + rr) * D_INNER + by + c] = t[rr][c];
    }
}

// Wfull rows 1536..1663: rows <1568 = fp16(xpw row), rows >=1568 = 0
__global__ __launch_bounds__(256) void bc_pad(const float* __restrict__ xpw,
                                              ushort* __restrict__ Wfull) {
    int i = blockIdx.x * 256 + threadIdx.x;   // < 128*1536
    int row = 1536 + i / D_INNER, col = i % D_INNER;
    float v = (row < XDBL_N) ? xpw[(size_t)row * D_INNER + col] : 0.f;
    Wfull[(size_t)row * D_INNER + col] = f2h(v);
}

// ---------------- fp16 MFMA GEMM, 1 or 2 A-products ----------------
// C[m,n] = sum_k (Ah[+Al])[m,k]*Wh[n,k]
// OM=0: f32 -> Cf (ld ldc)
// OM=1: col<1536 -> fp16 -> Oh (x_in); col>=1536 -> fp16 silu -> Oh2 (gated z)
// OM=2: col<1536 -> softplus(v+bias) f32 -> Cf (delta); 1536<=col<1568 -> f32 -> Cf2 (ld 32, bc)
// OM=3: fp16 -> Oh (Wcomb rows)
template<int OM, int NPROD>
__global__ __launch_bounds__(256, (NPROD==1) ? 4 : 3) void gemm_h(
    const ushort* __restrict__ Ah, const ushort* __restrict__ Al,
    const ushort* __restrict__ Wh,
    const float* __restrict__ bias,
    float* __restrict__ Cf, float* __restrict__ Cf2, int ldc,
    ushort* __restrict__ Oh, ushort* __restrict__ Oh2,
    int N, int K)
{
    constexpr int NBUF = NPROD + 1;
    __shared__ ushort lds[NBUF][128*64];
    const int tid = threadIdx.x, lane = tid & 63, wave = tid >> 6;
    // XCD swizzle (requires nwg % 8 == 0), bm-chunked per XCD
    const int gx = gridDim.x, nwg = gx * gridDim.y;
    const int lid = blockIdx.y * gx + blockIdx.x;
    const int swz = (lid & 7) * (nwg >> 3) + (lid >> 3);
    const int bm = (swz / gx) * 128, bn = (swz % gx) * 128;
    const int wr = wave >> 1, wc = wave & 1;
    const int r15 = lane & 15, q = lane >> 4;
    const int xorv = (lane & 7) << 4;
    f32x4 acc[4][4] = {};

    int srowv[4], scolb[4], soff[4];
    #pragma unroll
    for (int i = 0; i < 4; ++i) {
        int off = wave*4096 + i*1024 + lane*16;
        int row = off >> 7;
        srowv[i] = row;
        scolb[i] = (off & 127) ^ ((row & 7) << 4);
        soff[i]  = wave*4096 + i*1024;
    }

    for (int k0 = 0; k0 < K; k0 += 64) {
        if (k0) __syncthreads();
        #pragma unroll
        for (int i = 0; i < 4; ++i) {
            size_t arow = ((size_t)(bm + srowv[i]) * K + k0) * 2;
            size_t brow = ((size_t)(bn + srowv[i]) * K + k0) * 2;
            __builtin_amdgcn_global_load_lds((as1cv)((const char*)Ah + arow + scolb[i]),
                                             (as3v)((char*)lds[0] + soff[i]), 16, 0, 0);
            if constexpr (NPROD == 2)
                __builtin_amdgcn_global_load_lds((as1cv)((const char*)Al + arow + scolb[i]),
                                                 (as3v)((char*)lds[1] + soff[i]), 16, 0, 0);
            __builtin_amdgcn_global_load_lds((as1cv)((const char*)Wh + brow + scolb[i]),
                                             (as3v)((char*)lds[NBUF-1] + soff[i]), 16, 0, 0);
        }
        __syncthreads();
        #pragma unroll
        for (int kk = 0; kk < 2; ++kk) {
            const int kb = kk*64 + q*16;
            f16x8 ah[4], al[4], wh[4];
            #pragma unroll
            for (int m = 0; m < 4; ++m) {
                int row = wr*64 + m*16 + r15;
                int sc = row*128 + (kb ^ xorv);
                ah[m] = *(const f16x8*)((const char*)lds[0] + sc);
                if constexpr (NPROD == 2)
                    al[m] = *(const f16x8*)((const char*)lds[1] + sc);
            }
            #pragma unroll
            for (int n = 0; n < 4; ++n) {
                int row = wc*64 + n*16 + r15;
                int sc = row*128 + (kb ^ xorv);
                wh[n] = *(const f16x8*)((const char*)lds[NBUF-1] + sc);
            }
            #pragma unroll
            for (int m = 0; m < 4; ++m)
                #pragma unroll
                for (int n = 0; n < 4; ++n) {
                    acc[m][n] = __builtin_amdgcn_mfma_f32_16x16x32_f16(ah[m], wh[n], acc[m][n], 0, 0, 0);
                    if constexpr (NPROD == 2)
                        acc[m][n] = __builtin_amdgcn_mfma_f32_16x16x32_f16(al[m], wh[n], acc[m][n], 0, 0, 0);
                }
        }
    }

    #pragma unroll
    for (int m = 0; m < 4; ++m) {
        #pragma unroll
        for (int n = 0; n < 4; ++n) {
            int col = bn + wc*64 + n*16 + r15;
            if (col >= N) continue;
            #pragma unroll
            for (int r = 0; r < 4; ++r) {
                int rowg = bm + wr*64 + m*16 + q*4 + r;
                float v = acc[m][n][r];
                if constexpr (OM == 0) {
                    Cf[(size_t)rowg * ldc + col] = v;
                } else if constexpr (OM == 1) {
                    if (col < D_INNER) Oh[(size_t)rowg * D_INNER + col] = f2h(v);
                    else Oh2[(size_t)rowg * D_INNER + (col - D_INNER)] = f2h(silu_f(v));
                } else if constexpr (OM == 2) {
                    if (col < D_INNER) {
                        float t = v + bias[col];
                        Cf[(size_t)rowg * D_INNER + col] = (t > 20.f) ? t : log1pf(__expf(t));
                    } else if (col < XDBL_N) {
                        Cf2[(size_t)rowg * 32 + (col - D_INNER)] = v;
                    }
                } else {   // OM == 3
                    Oh[(size_t)rowg * D_INNER + col] = f2h(v);
                }
            }
        }
    }
}

// ---------------- depthwise causal conv (k=4, fp16 in) + bias + SiLU -> fp16 ----------------
__global__ __launch_bounds__(256) void conv_silu(
    const ushort* __restrict__ xin,  // (M_ROWS, 1536) fp16
    const float* __restrict__ cw, const float* __restrict__ cb,
    ushort* __restrict__ xch)
{
    int idx = blockIdx.x * 256 + threadIdx.x;   // over M_ROWS * 384
    int d4  = idx % (D_INNER / 4);
    int row = idx / (D_INNER / 4);
    int l = row & (SEQ - 1);
    int d = d4 * 4;
    float4 acc = make_float4(cb[d], cb[d+1], cb[d+2], cb[d+3]);
    #pragma unroll
    for (int jj = 0; jj < D_CONV; ++jj) {
        int ls = l + jj - (D_CONV - 1);
        if (ls >= 0) {
            const ushort4 xv = *reinterpret_cast<const ushort4*>(
                &xin[(size_t)(row + jj - (D_CONV - 1)) * D_INNER + d]);
            acc.x = fmaf(h2f(xv.x), cw[(d+0)*D_CONV + jj], acc.x);
            acc.y = fmaf(h2f(xv.y), cw[(d+1)*D_CONV + jj], acc.y);
            acc.z = fmaf(h2f(xv.z), cw[(d+2)*D_CONV + jj], acc.z);
            acc.w = fmaf(h2f(xv.w), cw[(d+3)*D_CONV + jj], acc.w);
        }
    }
    ushort4 h;
    h.x = f2h(silu_f(acc.x)); h.y = f2h(silu_f(acc.y));
    h.z = f2h(silu_f(acc.z)); h.w = f2h(silu_f(acc.w));
    ((ushort4*)xch)[((size_t)row * D_INNER + d) >> 2] = h;
}

// ---------------- chunked selective scan (CH=16, NCHUNK=128) ----------------
__global__ __launch_bounds__(256, 4) void scan_pass1(
    const float* __restrict__ delta,   // (M_ROWS,1536) f32
    const float* __restrict__ bc,      // (M_ROWS,32): B at +0, C at +16
    const ushort* __restrict__ xch,    // fp16 x_conv
    const float* __restrict__ A_log,
    ushort* __restrict__ Pc, ushort* __restrict__ Hc)   // fp16 checkpoints
{
    const int blk = blockIdx.x;
    const int dg = blk % DGRP;
    const int c  = (blk / DGRP) % NCHUNK;
    const int b  = blk / (DGRP * NCHUNK);
    const int d  = dg * 256 + threadIdx.x;
    const int row0 = b * SEQ + c * CH;

    float AregL2[D_STATE];
    #pragma unroll
    for (int r = 0; r < 4; ++r) {
        float4 a = *(const float4*)&A_log[d * D_STATE + r * 4];
        AregL2[r*4+0] = -__builtin_exp2f(a.x * LOG2E) * LOG2E;
        AregL2[r*4+1] = -__builtin_exp2f(a.y * LOG2E) * LOG2E;
        AregL2[r*4+2] = -__builtin_exp2f(a.z * LOG2E) * LOG2E;
        AregL2[r*4+3] = -__builtin_exp2f(a.w * LOG2E) * LOG2E;
    }

    float dl[CH], xc[CH];
    #pragma unroll
    for (int j = 0; j < CH; ++j)
        dl[j] = delta[(size_t)(row0 + j) * D_INNER + d];
    #pragma unroll
    for (int j = 0; j < CH; ++j)
        xc[j] = h2f(xch[(size_t)(row0 + j) * D_INNER + d]);

    float h[D_STATE] = {};
    float sumdlt = 0.f;
    #pragma unroll
    for (int j = 0; j < CH; ++j) {
        const float dlt = dl[j];
        const float dbx = dlt * xc[j];
        sumdlt += dlt;
        const float* brow = bc + (size_t)(row0 + j) * 32;   // block-uniform -> s_load
        #pragma unroll
        for (int n = 0; n < D_STATE; ++n)
            h[n] = fmaf(__builtin_exp2f(dlt * AregL2[n]), h[n], dbx * brow[n]);
    }

    size_t o = ((size_t)(b * NCHUNK + c) * D_INNER + d) * D_STATE;
    #pragma unroll
    for (int r = 0; r < 2; ++r) {
        ushort8v hv, pv;
        #pragma unroll
        for (int i = 0; i < 8; ++i) {
            hv[i] = f2h(h[r*8 + i]);
            pv[i] = f2h(__builtin_exp2f(AregL2[r*8 + i] * sumdlt));
        }
        ((ushort8v*)(Hc + o))[r] = hv;
        ((ushort8v*)(Pc + o))[r] = pv;
    }
}

__global__ __launch_bounds__(256) void scan_pass2(
    ushort* __restrict__ Pc, const ushort* __restrict__ Hc)
{
    int t = blockIdx.x * 256 + threadIdx.x;     // < BATCH * D_INNER * D_STATE
    int b = t / (D_INNER * D_STATE);
    int dn = t % (D_INNER * D_STATE);
    float h = 0.f;
    for (int c = 0; c < NCHUNK; ++c) {
        size_t o = (size_t)(b * NCHUNK + c) * (D_INNER * D_STATE) + dn;
        float P  = h2f(Pc[o]);
        float hc = h2f(Hc[o]);
        Pc[o] = f2h(h);            // Hin for chunk c
        h = fmaf(P, h, hc);
    }
}

// pass3: replay with true h_in; y = (sum_n h*C + xc*D)*gate -> single fp16 to yh
__global__ __launch_bounds__(256, 4) void scan_pass3(
    const float* __restrict__ delta, const float* __restrict__ bc,
    const ushort* __restrict__ xch,
    const ushort* __restrict__ zg,     // gated z = fp16(silu(z))
    const float* __restrict__ A_log, const float* __restrict__ Dpar,
    const ushort* __restrict__ Hin,    // fp16
    ushort* __restrict__ yh)
{
    const int blk = blockIdx.x;
    const int dg = blk % DGRP;
    const int c  = (blk / DGRP) % NCHUNK;
    const int b  = blk / (DGRP * NCHUNK);
    const int d  = dg * 256 + threadIdx.x;
    const int row0 = b * SEQ + c * CH;

    float AregL2[D_STATE];
    #pragma unroll
    for (int r = 0; r < 4; ++r) {
        float4 a = *(const float4*)&A_log[d * D_STATE + r * 4];
        AregL2[r*4+0] = -__builtin_exp2f(a.x * LOG2E) * LOG2E;
        AregL2[r*4+1] = -__builtin_exp2f(a.y * LOG2E) * LOG2E;
        AregL2[r*4+2] = -__builtin_exp2f(a.z * LOG2E) * LOG2E;
        AregL2[r*4+3] = -__builtin_exp2f(a.w * LOG2E) * LOG2E;
    }
    const float Dv = Dpar[d];

    float dl[CH], xc[CH];
    #pragma unroll
    for (int j = 0; j < CH; ++j)
        dl[j] = delta[(size_t)(row0 + j) * D_INNER + d];
    #pragma unroll
    for (int j = 0; j < CH; ++j)
        xc[j] = h2f(xch[(size_t)(row0 + j) * D_INNER + d]);

    float h[D_STATE];
    {
        size_t o = ((size_t)(b * NCHUNK + c) * D_INNER + d) * D_STATE;
        #pragma unroll
        for (int r = 0; r < 2; ++r) {
            ushort8v v = ((const ushort8v*)(Hin + o))[r];
            #pragma unroll
            for (int i = 0; i < 8; ++i) h[r*8 + i] = h2f(v[i]);
        }
    }

    #pragma unroll
    for (int j = 0; j < CH; ++j) {
        const float dlt = dl[j];
        const float dbx = dlt * xc[j];
        const float* brow = bc + (size_t)(row0 + j) * 32;   // block-uniform -> s_load
        #pragma unroll
        for (int n = 0; n < D_STATE; ++n)
            h[n] = fmaf(__builtin_exp2f(dlt * AregL2[n]), h[n], dbx * brow[n]);
        float p0 = 0.f, p1 = 0.f, p2 = 0.f, p3 = 0.f;
        #pragma unroll
        for (int n = 0; n < 4; ++n) {
            p0 = fmaf(h[n],      brow[16 + n],      p0);
            p1 = fmaf(h[4 + n],  brow[16 + 4 + n],  p1);
            p2 = fmaf(h[8 + n],  brow[16 + 8 + n],  p2);
            p3 = fmaf(h[12 + n], brow[16 + 12 + n], p3);
        }
        size_t ro = (size_t)(row0 + j) * D_INNER + d;
        const float gate = h2f(zg[ro]);
        const float y = ((p0 + p1) + (p2 + p3) + xc[j] * Dv) * gate;
        yh[ro] = f2h(y);
    }
}

extern "C" void kernel_launch(void* const* d_in, const int* in_sizes, int n_in,
                              void* d_out, int out_size, void* d_ws, size_t ws_size,
                              hipStream_t stream) {
    const float* x         = (const float*)d_in[0];
    const float* in_proj_w = (const float*)d_in[1];
    const float* conv_w    = (const float*)d_in[2];
    const float* conv_b    = (const float*)d_in[3];
    const float* x_proj_w  = (const float*)d_in[4];
    const float* dt_proj_w = (const float*)d_in[5];
    const float* dt_proj_b = (const float*)d_in[6];
    const float* A_log     = (const float*)d_in[7];
    const float* D_param   = (const float*)d_in[8];
    const float* out_proj_w= (const float*)d_in[9];
    float* out = (float*)d_out;

    // x hi/lo fp16 lives in d_out (12.58 MB exactly; dead once GEMM1 ran)
    ushort* xh = (ushort*)d_out;
    ushort* xl = xh + (size_t)M_ROWS * D_MODEL;

    char* p = (char*)d_ws;
    float*  delta = (float*)p;  p += (size_t)M_ROWS * D_INNER * 4;   // 25.2 MB; first half doubles as xin fp16
    ushort* xin  = (ushort*)delta;                                    // fp16 x_in (dead after conv)
    ushort* zg   = (ushort*)p;  p += (size_t)M_ROWS * D_INNER * 2;   // silu(z) fp16
    float*  bc   = (float*)p;   p += (size_t)M_ROWS * 32 * 4;        // B/C ssm f32
    ushort* xch  = (ushort*)p;  p += (size_t)M_ROWS * D_INNER * 2;   // x_conv fp16
    ushort* yh   = (ushort*)p;  p += (size_t)M_ROWS * D_INNER * 2;   // y fp16
    ushort* inwh = (ushort*)p;  p += (size_t)XZ_LD * D_MODEL * 2;    // in_proj fp16
    ushort* Wfull= (ushort*)p;  p += (size_t)WFULL_R * D_INNER * 2;  // [Wcomb(1536); xpw_bc(32); pad(96)]
    ushort* xpwT = (ushort*)p;  p += (size_t)D_INNER * D_INNER * 2;  // xpw_delta^T fp16
    ushort* dtwh = (ushort*)p;  p += (size_t)D_INNER * D_INNER * 2;
    ushort* dtwl = (ushort*)p;  p += (size_t)D_INNER * D_INNER * 2;
    ushort* opwh = (ushort*)p;  p += (size_t)D_MODEL * D_INNER * 2;
    ushort* Pc   = (ushort*)p;  p += (size_t)BATCH * NCHUNK * D_INNER * D_STATE * 2;
    ushort* Hc   = (ushort*)p;  p += (size_t)BATCH * NCHUNK * D_INNER * D_STATE * 2;
    // total ~115 MB

    // ---- prep ----
    split4_h<<<3072, 256, 0, stream>>>(x, xh, xl, M_ROWS * D_MODEL / 4);
    convh4  <<<2304, 256, 0, stream>>>(in_proj_w, inwh, XZ_LD * D_MODEL / 4);
    transpose_h<<<dim3(24,24), 256, 0, stream>>>(x_proj_w, xpwT);
    bc_pad  <<<768, 256, 0, stream>>>(x_proj_w, Wfull);
    split4_h<<<2304, 256, 0, stream>>>(dt_proj_w, dtwh, dtwl, D_INNER * D_INNER / 4);
    convh4  <<<1152, 256, 0, stream>>>(out_proj_w, opwh, D_MODEL * D_INNER / 4);

    // ---- W_comb = dt_proj_w @ xpw_delta  (rows 0..1535 of Wfull) ----
    gemm_h<3,2><<<dim3(12,12), 256, 0, stream>>>(
        dtwh, dtwl, xpwT, nullptr, nullptr, nullptr, D_INNER, Wfull, nullptr, D_INNER, D_INNER);

    // ---- 1) xz = x @ in_proj^T: x_in fp16 + zg = fp16(silu(z)) ----
    gemm_h<1,2><<<dim3(24,32), 256, 0, stream>>>(
        xh, xl, inwh, nullptr, nullptr, nullptr, XZ_LD, xin, zg, XZ_LD, D_MODEL);

    // ---- 2) x_conv (fp16 in/out) ----
    conv_silu<<<6144, 256, 0, stream>>>(xin, conv_w, conv_b, xch);

    // ---- 3+4 fused) delta = softplus(xc @ Wcomb^T + b) f32; bc cols f32 ----
    gemm_h<2,1><<<dim3(13,32), 256, 0, stream>>>(
        xch, nullptr, Wfull, dt_proj_b, delta, bc, D_INNER, nullptr, nullptr, XDBL_N, D_INNER);

    // ---- 5) chunked scan ----
    scan_pass1<<<BATCH * NCHUNK * DGRP, 256, 0, stream>>>(delta, bc, xch, A_log, Pc, Hc);
    scan_pass2<<<(BATCH * D_INNER * D_STATE) / 256, 256, 0, stream>>>(Pc, Hc);
    scan_pass3<<<BATCH * NCHUNK * DGRP, 256, 0, stream>>>(
        delta, bc, xch, zg, A_log, D_param, Pc, yh);

    // ---- 6) out = y @ out_proj^T ----
    gemm_h<0,1><<<dim3(6,32), 256, 0, stream>>>(
        yh, nullptr, opwh, nullptr, out, nullptr, D_MODEL, nullptr, nullptr, D_MODEL, D_INNER);
}

// Round 6
// 287.191 us; speedup vs baseline: 5.7951x; 1.1318x over previous
//
#include <hip/hip_runtime.h>
#include <hip/hip_fp16.h>
#include <cstdint>

#define D_MODEL 768
#define D_STATE 16
#define D_CONV  4
#define D_INNER 1536
#define BATCH   2
#define SEQ     2048
#define M_ROWS  (BATCH*SEQ)            // 4096
#define XZ_LD   (2*D_INNER)            // 3072
#define XDBL_N  (D_INNER + 2*D_STATE)  // 1568
#define WFULL_R 1664                   // 1568 padded to 26*64
#define NCHUNK  128
#define CH      16
#define DGRP    (D_INNER/256)          // 6

typedef __attribute__((ext_vector_type(8))) _Float16 f16x8;
typedef __attribute__((ext_vector_type(4))) float f32x4;
typedef __attribute__((ext_vector_type(8))) ushort ushort8v;
typedef const __attribute__((address_space(1))) void* as1cv;
typedef __attribute__((address_space(3))) void* as3v;

#define LOG2E 1.44269504088896f

__device__ __forceinline__ ushort f2h(float f) { return __half_as_ushort(__float2half(f)); }
__device__ __forceinline__ float h2f(ushort u) { return __half2float(__ushort_as_half(u)); }
__device__ __forceinline__ float silu_f(float v) {
    return v / (1.f + __builtin_exp2f(-v * LOG2E));
}
// branch-free softplus via v_exp_f32/v_log_f32
__device__ __forceinline__ float softplus_f(float t) {
    float e = __builtin_exp2f(-fabsf(t) * LOG2E);
    return fmaxf(t, 0.f) + __log2f(1.f + e) * 0.69314718056f;
}

// ---------------- prep kernels ----------------
__global__ __launch_bounds__(256) void convh4(const float* __restrict__ src,
                                              ushort* __restrict__ dst, int n4) {
    int i = blockIdx.x * 256 + threadIdx.x;
    if (i >= n4) return;
    float4 v = ((const float4*)src)[i];
    ushort4 h;
    h.x = f2h(v.x); h.y = f2h(v.y); h.z = f2h(v.z); h.w = f2h(v.w);
    ((ushort4*)dst)[i] = h;
}

// transpose 1536x1536 f32 -> fp16: dst[j][i] = src[i][j]
__global__ __launch_bounds__(256) void transpose_h(const float* __restrict__ src,
                                                   ushort* __restrict__ dst) {
    __shared__ ushort t[64][65];
    const int bx = blockIdx.x * 64;
    const int by = blockIdx.y * 64;
    const int c = threadIdx.x & 63, r0 = threadIdx.x >> 6;
    #pragma unroll
    for (int i = 0; i < 16; ++i) {
        int r = r0 + i * 4;
        t[c][r] = f2h(src[(size_t)(by + r) * D_INNER + bx + c]);
    }
    __syncthreads();
    #pragma unroll
    for (int i = 0; i < 16; ++i) {
        int rr = r0 + i * 4;
        dst[(size_t)(bx + rr) * D_INNER + by + c] = t[rr][c];
    }
}

// Wfull rows 1536..1663: rows <1568 = fp16(xpw row), rows >=1568 = 0
__global__ __launch_bounds__(256) void bc_pad(const float* __restrict__ xpw,
                                              ushort* __restrict__ Wfull) {
    int i = blockIdx.x * 256 + threadIdx.x;   // < 128*1536
    int row = 1536 + i / D_INNER, col = i % D_INNER;
    float v = (row < XDBL_N) ? xpw[(size_t)row * D_INNER + col] : 0.f;
    Wfull[(size_t)row * D_INNER + col] = f2h(v);
}

// split-K partial reducers
__global__ __launch_bounds__(256) void reduce_add_h(const float* __restrict__ Cp, size_t zstride,
                                                    ushort* __restrict__ dst, int n4) {
    int i = blockIdx.x * 256 + threadIdx.x;
    if (i >= n4) return;
    float4 a = ((const float4*)Cp)[i];
    float4 b = ((const float4*)(Cp + zstride))[i];
    ushort4 h;
    h.x = f2h(a.x + b.x); h.y = f2h(a.y + b.y); h.z = f2h(a.z + b.z); h.w = f2h(a.w + b.w);
    ((ushort4*)dst)[i] = h;
}
__global__ __launch_bounds__(256) void reduce_add_f(const float* __restrict__ Cp, size_t zstride,
                                                    float* __restrict__ dst, int n4) {
    int i = blockIdx.x * 256 + threadIdx.x;
    if (i >= n4) return;
    float4 a = ((const float4*)Cp)[i];
    float4 b = ((const float4*)(Cp + zstride))[i];
    a.x += b.x; a.y += b.y; a.z += b.z; a.w += b.w;
    ((float4*)dst)[i] = a;
}

// ---------------- fp16 MFMA GEMM, 128x64 tile, double-buffered 2-phase pipeline ----------------
// C[m,n] = sum_k A[m,k]*W[n,k]
// OM=1: col<1536 -> fp16 Oh (x_in); col>=1536 -> fp16 silu -> Oh2 (gated z)
// OM=2: col<1536 -> fp16 softplus(v+bias) -> Oh (delta); 1536<=col<1568 -> f32 Cf2 (ld 32, bc)
// OM=4: f32 partial -> Cf[z*zstride + row*N + col]   (split-K, NZ=2)
template<int OM, int NZ>
__global__ __launch_bounds__(256) void gemm_h(
    const ushort* __restrict__ A, const ushort* __restrict__ W,
    const float* __restrict__ bias,
    float* __restrict__ Cf, float* __restrict__ Cf2,
    ushort* __restrict__ Oh, ushort* __restrict__ Oh2,
    int N, int K, size_t zstride)
{
    __shared__ ushort As[2][128*64];   // 2 x 16 KB
    __shared__ ushort Ws[2][64*64];    // 2 x  8 KB  -> 48 KB total, 3 blocks/CU
    const int tid = threadIdx.x, lane = tid & 63, wave = tid >> 6;
    // XCD swizzle (nwg % 8 == 0 for all our grids), bm-chunked per XCD
    const int gx = gridDim.x, nwg = gx * gridDim.y;
    const int lid = blockIdx.y * gx + blockIdx.x;
    const int swz = (lid & 7) * (nwg >> 3) + (lid >> 3);
    const int bm = (swz / gx) * 128, bn = (swz % gx) * 64;
    const int wr = wave >> 1, wc = wave & 1;
    const int r15 = lane & 15, q = lane >> 4;
    const int xorv = (lane & 7) << 4;
    f32x4 acc[4][2] = {};

    const int Kp = K / NZ;
    const int kbeg = (NZ > 1) ? blockIdx.z * Kp : 0;

    // staging geometry: linear LDS dest, pre-swizzled global source col (rule 21)
    int aRow[4], aCol[4], aOff[4];
    #pragma unroll
    for (int i = 0; i < 4; ++i) {
        int off = wave*4096 + i*1024 + lane*16;
        int row = off >> 7;
        aRow[i] = row;
        aCol[i] = (off & 127) ^ ((row & 7) << 4);
        aOff[i] = wave*4096 + i*1024;
    }
    int wRowi[2], wColi[2], wOffi[2];
    #pragma unroll
    for (int i = 0; i < 2; ++i) {
        int off = wave*2048 + i*1024 + lane*16;
        int row = off >> 7;
        wRowi[i] = row;
        wColi[i] = (off & 127) ^ ((row & 7) << 4);
        wOffi[i] = wave*2048 + i*1024;
    }

    auto STAGE = [&](int b, int k0) {
        #pragma unroll
        for (int i = 0; i < 4; ++i) {
            size_t ar = ((size_t)(bm + aRow[i]) * K + kbeg + k0) * 2;
            __builtin_amdgcn_global_load_lds((as1cv)((const char*)A + ar + aCol[i]),
                                             (as3v)((char*)As[b] + aOff[i]), 16, 0, 0);
        }
        #pragma unroll
        for (int i = 0; i < 2; ++i) {
            size_t wr_ = ((size_t)(bn + wRowi[i]) * K + kbeg + k0) * 2;
            __builtin_amdgcn_global_load_lds((as1cv)((const char*)W + wr_ + wColi[i]),
                                             (as3v)((char*)Ws[b] + wOffi[i]), 16, 0, 0);
        }
    };

    STAGE(0, 0);
    __syncthreads();
    int cur = 0;
    const int nt = Kp / 64;
    for (int t = 0; t < nt; ++t) {
        if (t + 1 < nt) STAGE(cur ^ 1, (t + 1) * 64);   // prefetch overlaps compute
        #pragma unroll
        for (int kk = 0; kk < 2; ++kk) {
            const int kb = kk*64 + q*16;
            f16x8 af[4], wf[2];
            #pragma unroll
            for (int m = 0; m < 4; ++m) {
                int row = wr*64 + m*16 + r15;
                af[m] = *(const f16x8*)((const char*)As[cur] + row*128 + (kb ^ xorv));
            }
            #pragma unroll
            for (int n = 0; n < 2; ++n) {
                int row = wc*32 + n*16 + r15;
                wf[n] = *(const f16x8*)((const char*)Ws[cur] + row*128 + (kb ^ xorv));
            }
            #pragma unroll
            for (int m = 0; m < 4; ++m)
                #pragma unroll
                for (int n = 0; n < 2; ++n)
                    acc[m][n] = __builtin_amdgcn_mfma_f32_16x16x32_f16(af[m], wf[n], acc[m][n], 0, 0, 0);
        }
        __syncthreads();
        cur ^= 1;
    }

    #pragma unroll
    for (int m = 0; m < 4; ++m) {
        #pragma unroll
        for (int n = 0; n < 2; ++n) {
            int col = bn + wc*32 + n*16 + r15;
            #pragma unroll
            for (int r = 0; r < 4; ++r) {
                int rowg = bm + wr*64 + m*16 + q*4 + r;
                float v = acc[m][n][r];
                if constexpr (OM == 1) {
                    if (col < D_INNER) Oh[(size_t)rowg * D_INNER + col] = f2h(v);
                    else Oh2[(size_t)rowg * D_INNER + (col - D_INNER)] = f2h(silu_f(v));
                } else if constexpr (OM == 2) {
                    if (col < D_INNER) {
                        Oh[(size_t)rowg * D_INNER + col] = f2h(softplus_f(v + bias[col]));
                    } else if (col < XDBL_N) {
                        Cf2[(size_t)rowg * 32 + (col - D_INNER)] = v;
                    }
                } else {   // OM == 4: f32 split-K partial
                    Cf[(size_t)blockIdx.z * zstride + (size_t)rowg * N + col] = v;
                }
            }
        }
    }
}

// ---------------- depthwise causal conv (k=4, fp16 in) + bias + SiLU -> fp16 ----------------
__global__ __launch_bounds__(256) void conv_silu(
    const ushort* __restrict__ xin,  // (M_ROWS, 1536) fp16
    const float* __restrict__ cw, const float* __restrict__ cb,
    ushort* __restrict__ xch)
{
    int idx = blockIdx.x * 256 + threadIdx.x;   // over M_ROWS * 384
    int d4  = idx % (D_INNER / 4);
    int row = idx / (D_INNER / 4);
    int l = row & (SEQ - 1);
    int d = d4 * 4;
    float4 acc = make_float4(cb[d], cb[d+1], cb[d+2], cb[d+3]);
    #pragma unroll
    for (int jj = 0; jj < D_CONV; ++jj) {
        int ls = l + jj - (D_CONV - 1);
        if (ls >= 0) {
            const ushort4 xv = *reinterpret_cast<const ushort4*>(
                &xin[(size_t)(row + jj - (D_CONV - 1)) * D_INNER + d]);
            acc.x = fmaf(h2f(xv.x), cw[(d+0)*D_CONV + jj], acc.x);
            acc.y = fmaf(h2f(xv.y), cw[(d+1)*D_CONV + jj], acc.y);
            acc.z = fmaf(h2f(xv.z), cw[(d+2)*D_CONV + jj], acc.z);
            acc.w = fmaf(h2f(xv.w), cw[(d+3)*D_CONV + jj], acc.w);
        }
    }
    ushort4 h;
    h.x = f2h(silu_f(acc.x)); h.y = f2h(silu_f(acc.y));
    h.z = f2h(silu_f(acc.z)); h.w = f2h(silu_f(acc.w));
    ((ushort4*)xch)[((size_t)row * D_INNER + d) >> 2] = h;
}

// ---------------- chunked selective scan (CH=16, NCHUNK=128) ----------------
__global__ __launch_bounds__(256, 4) void scan_pass1(
    const ushort* __restrict__ delta,  // (M_ROWS,1536) fp16
    const float* __restrict__ bc,      // (M_ROWS,32): B at +0, C at +16
    const ushort* __restrict__ xch,    // fp16 x_conv
    const float* __restrict__ A_log,
    ushort* __restrict__ Pc, ushort* __restrict__ Hc)   // fp16 checkpoints
{
    const int blk = blockIdx.x;
    const int dg = blk % DGRP;
    const int c  = (blk / DGRP) % NCHUNK;
    const int b  = blk / (DGRP * NCHUNK);
    const int d  = dg * 256 + threadIdx.x;
    const int row0 = b * SEQ + c * CH;

    float AregL2[D_STATE];
    #pragma unroll
    for (int r = 0; r < 4; ++r) {
        float4 a = *(const float4*)&A_log[d * D_STATE + r * 4];
        AregL2[r*4+0] = -__builtin_exp2f(a.x * LOG2E) * LOG2E;
        AregL2[r*4+1] = -__builtin_exp2f(a.y * LOG2E) * LOG2E;
        AregL2[r*4+2] = -__builtin_exp2f(a.z * LOG2E) * LOG2E;
        AregL2[r*4+3] = -__builtin_exp2f(a.w * LOG2E) * LOG2E;
    }

    float dl[CH], xc[CH];
    #pragma unroll
    for (int j = 0; j < CH; ++j)
        dl[j] = h2f(delta[(size_t)(row0 + j) * D_INNER + d]);
    #pragma unroll
    for (int j = 0; j < CH; ++j)
        xc[j] = h2f(xch[(size_t)(row0 + j) * D_INNER + d]);

    float h[D_STATE] = {};
    float sumdlt = 0.f;
    #pragma unroll
    for (int j = 0; j < CH; ++j) {
        const float dlt = dl[j];
        const float dbx = dlt * xc[j];
        sumdlt += dlt;
        const float* brow = bc + (size_t)(row0 + j) * 32;   // block-uniform -> s_load
        #pragma unroll
        for (int n = 0; n < D_STATE; ++n)
            h[n] = fmaf(__builtin_exp2f(dlt * AregL2[n]), h[n], dbx * brow[n]);
    }

    size_t o = ((size_t)(b * NCHUNK + c) * D_INNER + d) * D_STATE;
    #pragma unroll
    for (int r = 0; r < 2; ++r) {
        ushort8v hv, pv;
        #pragma unroll
        for (int i = 0; i < 8; ++i) {
            hv[i] = f2h(h[r*8 + i]);
            pv[i] = f2h(__builtin_exp2f(AregL2[r*8 + i] * sumdlt));
        }
        ((ushort8v*)(Hc + o))[r] = hv;
        ((ushort8v*)(Pc + o))[r] = pv;
    }
}

__global__ __launch_bounds__(256) void scan_pass2(
    ushort* __restrict__ Pc, const ushort* __restrict__ Hc)
{
    int t = blockIdx.x * 256 + threadIdx.x;     // < BATCH * D_INNER * D_STATE
    int b = t / (D_INNER * D_STATE);
    int dn = t % (D_INNER * D_STATE);
    float h = 0.f;
    for (int c = 0; c < NCHUNK; ++c) {
        size_t o = (size_t)(b * NCHUNK + c) * (D_INNER * D_STATE) + dn;
        float P  = h2f(Pc[o]);
        float hc = h2f(Hc[o]);
        Pc[o] = f2h(h);            // Hin for chunk c
        h = fmaf(P, h, hc);
    }
}

// pass3: replay with true h_in; y = (sum_n h*C + xc*D)*gate -> fp16 yh
__global__ __launch_bounds__(256, 4) void scan_pass3(
    const ushort* __restrict__ delta, const float* __restrict__ bc,
    const ushort* __restrict__ xch,
    const ushort* __restrict__ zg,     // gated z = fp16(silu(z))
    const float* __restrict__ A_log, const float* __restrict__ Dpar,
    const ushort* __restrict__ Hin,    // fp16
    ushort* __restrict__ yh)
{
    const int blk = blockIdx.x;
    const int dg = blk % DGRP;
    const int c  = (blk / DGRP) % NCHUNK;
    const int b  = blk / (DGRP * NCHUNK);
    const int d  = dg * 256 + threadIdx.x;
    const int row0 = b * SEQ + c * CH;

    float AregL2[D_STATE];
    #pragma unroll
    for (int r = 0; r < 4; ++r) {
        float4 a = *(const float4*)&A_log[d * D_STATE + r * 4];
        AregL2[r*4+0] = -__builtin_exp2f(a.x * LOG2E) * LOG2E;
        AregL2[r*4+1] = -__builtin_exp2f(a.y * LOG2E) * LOG2E;
        AregL2[r*4+2] = -__builtin_exp2f(a.z * LOG2E) * LOG2E;
        AregL2[r*4+3] = -__builtin_exp2f(a.w * LOG2E) * LOG2E;
    }
    const float Dv = Dpar[d];

    float dl[CH], xc[CH];
    #pragma unroll
    for (int j = 0; j < CH; ++j)
        dl[j] = h2f(delta[(size_t)(row0 + j) * D_INNER + d]);
    #pragma unroll
    for (int j = 0; j < CH; ++j)
        xc[j] = h2f(xch[(size_t)(row0 + j) * D_INNER + d]);

    float h[D_STATE];
    {
        size_t o = ((size_t)(b * NCHUNK + c) * D_INNER + d) * D_STATE;
        #pragma unroll
        for (int r = 0; r < 2; ++r) {
            ushort8v v = ((const ushort8v*)(Hin + o))[r];
            #pragma unroll
            for (int i = 0; i < 8; ++i) h[r*8 + i] = h2f(v[i]);
        }
    }

    #pragma unroll
    for (int j = 0; j < CH; ++j) {
        const float dlt = dl[j];
        const float dbx = dlt * xc[j];
        const float* brow = bc + (size_t)(row0 + j) * 32;   // block-uniform -> s_load
        #pragma unroll
        for (int n = 0; n < D_STATE; ++n)
            h[n] = fmaf(__builtin_exp2f(dlt * AregL2[n]), h[n], dbx * brow[n]);
        float p0 = 0.f, p1 = 0.f, p2 = 0.f, p3 = 0.f;
        #pragma unroll
        for (int n = 0; n < 4; ++n) {
            p0 = fmaf(h[n],      brow[16 + n],      p0);
            p1 = fmaf(h[4 + n],  brow[16 + 4 + n],  p1);
            p2 = fmaf(h[8 + n],  brow[16 + 8 + n],  p2);
            p3 = fmaf(h[12 + n], brow[16 + 12 + n], p3);
        }
        size_t ro = (size_t)(row0 + j) * D_INNER + d;
        const float gate = h2f(zg[ro]);
        const float y = ((p0 + p1) + (p2 + p3) + xc[j] * Dv) * gate;
        yh[ro] = f2h(y);
    }
}

extern "C" void kernel_launch(void* const* d_in, const int* in_sizes, int n_in,
                              void* d_out, int out_size, void* d_ws, size_t ws_size,
                              hipStream_t stream) {
    const float* x         = (const float*)d_in[0];
    const float* in_proj_w = (const float*)d_in[1];
    const float* conv_w    = (const float*)d_in[2];
    const float* conv_b    = (const float*)d_in[3];
    const float* x_proj_w  = (const float*)d_in[4];
    const float* dt_proj_w = (const float*)d_in[5];
    const float* dt_proj_b = (const float*)d_in[6];
    const float* A_log     = (const float*)d_in[7];
    const float* D_param   = (const float*)d_in[8];
    const float* out_proj_w= (const float*)d_in[9];
    float* out = (float*)d_out;

    // x fp16 lives in d_out (6.29 MB of 12.58; dead once GEMM1 ran; out fully overwritten at the end)
    ushort* xh = (ushort*)d_out;

    char* p = (char*)d_ws;
    ushort* xin  = (ushort*)p;  p += (size_t)M_ROWS * D_INNER * 2;   // x_in fp16; later delta fp16 (alias)
    ushort* zg   = (ushort*)p;  p += (size_t)M_ROWS * D_INNER * 2;   // silu(z) fp16
    float*  bc   = (float*)p;   p += (size_t)M_ROWS * 32 * 4;        // B/C ssm f32
    ushort* xch  = (ushort*)p;  p += (size_t)M_ROWS * D_INNER * 2;   // x_conv fp16
    ushort* yh   = (ushort*)p;  p += (size_t)M_ROWS * D_INNER * 2;   // y fp16
    ushort* inwh = (ushort*)p;  p += (size_t)XZ_LD * D_MODEL * 2;    // in_proj fp16
    ushort* Wfull= (ushort*)p;  p += (size_t)WFULL_R * D_INNER * 2;  // [Wcomb(1536); xpw_bc(32); pad(96)]
    ushort* xpwT = (ushort*)p;  p += (size_t)D_INNER * D_INNER * 2;  // xpw^T fp16
    ushort* dtwh = (ushort*)p;  p += (size_t)D_INNER * D_INNER * 2;  // dt_proj fp16
    ushort* opwh = (ushort*)p;  p += (size_t)D_MODEL * D_INNER * 2;  // out_proj fp16
    // time-shared 25.17 MB scratch: CpW (Wcomb partials) -> Pc+Hc (scan) -> Cp6 (GEMM6 partials)
    float*  scratch = (float*)p;  p += (size_t)2 * M_ROWS * D_MODEL * 4;

    ushort* delta = xin;                      // delta overwrites x_in (dead after conv)
    float*  CpW = scratch;                    // 2 x 1536x1536 f32 = 18.9 MB
    ushort* Pc  = (ushort*)scratch;           // 12.58 MB
    ushort* Hc  = Pc + (size_t)BATCH * NCHUNK * D_INNER * D_STATE;
    float*  Cp6 = scratch;                    // 2 x 4096x768 f32 = 25.17 MB

    // ---- prep: fp16 conversions ----
    convh4<<<3072, 256, 0, stream>>>(x, xh, M_ROWS * D_MODEL / 4);
    convh4<<<2304, 256, 0, stream>>>(in_proj_w, inwh, XZ_LD * D_MODEL / 4);
    transpose_h<<<dim3(24,24), 256, 0, stream>>>(x_proj_w, xpwT);
    bc_pad<<<768, 256, 0, stream>>>(x_proj_w, Wfull);
    convh4<<<2304, 256, 0, stream>>>(dt_proj_w, dtwh, D_INNER * D_INNER / 4);
    convh4<<<1152, 256, 0, stream>>>(out_proj_w, opwh, D_MODEL * D_INNER / 4);

    // ---- W_comb = dt_proj_w @ xpw_delta (split-K=2 -> reduce -> Wfull rows 0..1535) ----
    gemm_h<4,2><<<dim3(24,12,2), 256, 0, stream>>>(
        dtwh, xpwT, nullptr, CpW, nullptr, nullptr, nullptr,
        D_INNER, D_INNER, (size_t)D_INNER * D_INNER);
    reduce_add_h<<<2304, 256, 0, stream>>>(CpW, (size_t)D_INNER * D_INNER, Wfull,
                                           D_INNER * D_INNER / 4);

    // ---- 1) xz = x @ in_proj^T: x_in fp16 + zg = fp16(silu(z)) ----
    gemm_h<1,1><<<dim3(48,32), 256, 0, stream>>>(
        xh, inwh, nullptr, nullptr, nullptr, xin, zg, XZ_LD, D_MODEL, 0);

    // ---- 2) x_conv ----
    conv_silu<<<6144, 256, 0, stream>>>(xin, conv_w, conv_b, xch);

    // ---- 3+4 fused) delta = softplus(xc @ Wcomb^T + b) fp16 (over xin); bc f32 ----
    gemm_h<2,1><<<dim3(26,32), 256, 0, stream>>>(
        xch, Wfull, dt_proj_b, nullptr, bc, delta, nullptr, WFULL_R, D_INNER, 0);

    // ---- 5) chunked scan ----
    scan_pass1<<<BATCH * NCHUNK * DGRP, 256, 0, stream>>>(delta, bc, xch, A_log, Pc, Hc);
    scan_pass2<<<(BATCH * D_INNER * D_STATE) / 256, 256, 0, stream>>>(Pc, Hc);
    scan_pass3<<<BATCH * NCHUNK * DGRP, 256, 0, stream>>>(
        delta, bc, xch, zg, A_log, D_param, Pc, yh);

    // ---- 6) out = y @ out_proj^T (split-K=2 -> reduce -> out f32) ----
    gemm_h<4,2><<<dim3(12,32,2), 256, 0, stream>>>(
        yh, opwh, nullptr, Cp6, nullptr, nullptr, nullptr,
        D_MODEL, D_INNER, (size_t)M_ROWS * D_MODEL);
    reduce_add_f<<<3072, 256, 0, stream>>>(Cp6, (size_t)M_ROWS * D_MODEL, out,
                                           M_ROWS * D_MODEL / 4);
}